// Round 1
// baseline (304.844 us; speedup 1.0000x reference)
//
#include <hip/hip_runtime.h>
#include <cstdint>
#include <cstddef>

// ---------------------------------------------------------------------------
// GAT 3-layer forward, MI355X.
// Round 13: gemm_sgpr was latency-serialized (VGPR=28 -> ~1 x-load in flight;
// 48KB of W per wave streamed through the scalar cache with ~1-2 steps of
// SGPR prefetch). New GEMM: W preloaded into per-lane VGPRs once (lane holds
// row lane+64*ch of its wave's fout slice), broadcast per-k via v_readlane
// (pure VALU, zero scalar loads in the k-loop); x explicitly software-
// pipelined: 16-float chunks, 3-slot rotation, prefetch distance 2 (8 dwordx4
// in flight). All indexing compile-time (full unroll) so nothing spills.
// ---------------------------------------------------------------------------

__device__ __forceinline__ float leaky(float v) { return v > 0.f ? v : 0.2f * v; }

__device__ __forceinline__ unsigned short f2bf(float x) {
    unsigned int u = __float_as_uint(x);
    u = (u + 0x7FFFu + ((u >> 16) & 1u)) >> 16;   // RNE
    return (unsigned short)u;
}
__device__ __forceinline__ float bf2f(unsigned short b) {
    return __uint_as_float(((unsigned int)b) << 16);
}

#define BSHIFT 7                 // 128 nodes per bucket
#define BCAP   5120              // slots per bucket region (mean 4096, +16 sigma)
#define CTILE  8192              // edges per coarse block

// -------------------- coarse bin: edges -> bucket regions --------------------

__global__ __launch_bounds__(256) void coarse_bin_kernel(
    const int* __restrict__ ei, unsigned int* __restrict__ staged,
    int* __restrict__ gcursor, int E, int K) {
    __shared__ int hist[512];
    __shared__ int rank[512];
    __shared__ int base[512];
    for (int b = threadIdx.x; b < K; b += 256) { hist[b] = 0; rank[b] = 0; }
    __syncthreads();

    int e0 = blockIdx.x * CTILE;
    int e1 = min(E, e0 + CTILE);

    for (int e = e0 + threadIdx.x; e < e1; e += 256) {
        int d = ei[E + e];
        atomicAdd(&hist[d >> BSHIFT], 1);
    }
    __syncthreads();

    for (int b = threadIdx.x; b < K; b += 256) {
        int c = hist[b];
        base[b] = c ? atomicAdd(&gcursor[b], c) : 0;
    }
    __syncthreads();

    for (int e = e0 + threadIdx.x; e < e1; e += 256) {
        int s = ei[e];
        int d = ei[E + e];
        int b = d >> BSHIFT;
        int r = atomicAdd(&rank[b], 1);
        staged[(size_t)b * BCAP + base[b] + r] =
            ((unsigned int)(d & ((1 << BSHIFT) - 1)) << 16) | (unsigned int)s;
    }
}

// -------------------- bucket base scan (1 block) --------------------

__global__ __launch_bounds__(512) void bucket_scan_kernel(
    const int* __restrict__ gcursor, int* __restrict__ bbase, int K) {
    __shared__ int sh[512];
    int t = threadIdx.x;
    int v = (t < K) ? gcursor[t] : 0;
    sh[t] = v;
    __syncthreads();
    for (int off = 1; off < 512; off <<= 1) {
        int a = (t >= off) ? sh[t - off] : 0;
        __syncthreads();
        sh[t] += a;
        __syncthreads();
    }
    if (t < K) bbase[t] = sh[t] - v;   // exclusive
}

// -------------------- fine pass: bucket -> rowptr + sorted csr --------------------

__global__ __launch_bounds__(256) void fine_sort_kernel(
    const unsigned int* __restrict__ staged, const int* __restrict__ gcursor,
    const int* __restrict__ bbase, int* __restrict__ rowptr, int* __restrict__ csr,
    int N, int E) {
    __shared__ int cnt[128];
    __shared__ int off[128];
    __shared__ int lcsr[BCAP];
    const int b = blockIdx.x;
    const int t = threadIdx.x;
    const int c = gcursor[b];
    const int gb = bbase[b];
    const unsigned int* rec = staged + (size_t)b * BCAP;

    if (t < 128) cnt[t] = 0;
    __syncthreads();

    for (int i = t; i < c; i += 256) atomicAdd(&cnt[rec[i] >> 16], 1);
    __syncthreads();

    if (t < 128) off[t] = cnt[t];
    __syncthreads();
    for (int s = 1; s < 128; s <<= 1) {
        int a = (t >= s && t < 128) ? off[t - s] : 0;
        __syncthreads();
        if (t < 128) off[t] += a;
        __syncthreads();
    }

    if (t < 128) {
        int excl = off[t] - cnt[t];
        int n = (b << BSHIFT) + t;
        if (n <= N) rowptr[n] = gb + excl;
        cnt[t] = excl;
    }
    if (b == 0 && t == 0) rowptr[N] = E;
    __syncthreads();

    for (int i = t; i < c; i += 256) {
        unsigned int r = rec[i];
        int p = atomicAdd(&cnt[r >> 16], 1);
        lcsr[p] = (int)(r & 0xFFFFu);
    }
    __syncthreads();

    for (int i = t; i < c; i += 256) csr[gb + i] = lcsr[i];
}

// -------------------- fused GEMM + alpha (layers 1-2, bf16 H out) --------------------
// lane = node (64 nodes/block); wave wid handles fouts [wid*FT, (wid+1)*FT).
// W preloaded to per-lane VGPRs (lane holds rows {lane, lane+64, ...} of the
// wave's fout slice); per-k broadcast via v_readlane -> SGPR operand to
// v_fmac. ZERO memory ops for W in the k-loop. x pipelined: 16-float chunks,
// 3-slot rotation, prefetch distance 2 -> 8 dwordx4 in flight per wave.
// Alpha partials reduced across the 4 waves via 2KB LDS (no atomics).

__device__ __forceinline__ float rlane(float v, int ln) {
    return __uint_as_float(
        (unsigned int)__builtin_amdgcn_readlane((int)__float_as_uint(v), ln));
}

template <int FIN, int FOUT, int FT>
__global__ __launch_bounds__(256) void gemm_rl_kernel(
    const float* __restrict__ X, const float* __restrict__ W,
    const float* __restrict__ avs, const float* __restrict__ avd,
    unsigned short* __restrict__ hb, float* __restrict__ asrc, float* __restrict__ adst,
    int N) {
    static_assert(4 * FT == FOUT, "FT must be FOUT/4");
    static_assert(FIN % 16 == 0, "FIN multiple of 16");
    constexpr int NCH = FIN / 16;          // x chunks (16 floats each)
    constexpr int WCH = (FIN + 63) / 64;   // W row chunks (64 rows each)
    __shared__ float red[2][4][64];

    const int wid  = __builtin_amdgcn_readfirstlane(threadIdx.x >> 6); // wave id 0..3
    const int lane = threadIdx.x & 63;
    const int n    = blockIdx.x * 64 + lane;
    const int nc   = (n < N) ? n : N - 1;     // clamp loads; stores guarded
    const int fbase = wid * FT;               // uniform

    const float* xrow = X + (size_t)nc * FIN;

    // ---- x pipeline: preload chunks 0,1 (issue first: longest latency) ----
    float xb[3][16];
#pragma unroll
    for (int s = 0; s < 2 && s < NCH; s++) {
#pragma unroll
        for (int q = 0; q < 4; q++)
            *(float4*)&xb[s][q * 4] = *(const float4*)(xrow + s * 16 + q * 4);
    }

    // ---- W preload: lane holds row (ch*64+lane), cols [fbase, fbase+FT) ----
    float wreg[WCH][FT];
#pragma unroll
    for (int ch = 0; ch < WCH; ch++) {
        int row = ch * 64 + lane;
        if (row >= FIN) row = FIN - 1;        // clamped rows never read back
        const float* wr = W + (size_t)row * FOUT + fbase;
#pragma unroll
        for (int c = 0; c < FT; c++) wreg[ch][c] = wr[c];
    }

    float acc[FT];
#pragma unroll
    for (int c = 0; c < FT; c++) acc[c] = 0.f;

#pragma unroll
    for (int j = 0; j < NCH; j++) {
        if (j + 2 < NCH) {                    // compile-time under full unroll
            constexpr int SH = 0;             // silence no-op
            (void)SH;
#pragma unroll
            for (int q = 0; q < 4; q++)
                *(float4*)&xb[(j + 2) % 3][q * 4] =
                    *(const float4*)(xrow + (j + 2) * 16 + q * 4);
        }
#pragma unroll
        for (int t = 0; t < 16; t++) {
            const int k = j * 16 + t;         // compile-time
            const float xv = xb[j % 3][t];
#pragma unroll
            for (int c = 0; c < FT; c++) {
                const float wv = rlane(wreg[k >> 6][c], k & 63);
                acc[c] = fmaf(xv, wv, acc[c]);
            }
        }
    }

    // alpha partials over this wave's fout subset (avs/avd loads are uniform)
    float ps = 0.f, pd = 0.f;
#pragma unroll
    for (int c = 0; c < FT; c++) {
        ps = fmaf(acc[c], avs[fbase + c], ps);
        pd = fmaf(acc[c], avd[fbase + c], pd);
    }
    red[0][wid][lane] = ps;
    red[1][wid][lane] = pd;

    // h store (bf16, padded 64-entry rows)
    if (n < N) {
        if constexpr ((FT & 1) == 0) {
            unsigned int* dst = (unsigned int*)(hb + (size_t)n * 64 + fbase);
#pragma unroll
            for (int c = 0; c < FT; c += 2) {
                unsigned int pk = (unsigned int)f2bf(acc[c]) |
                                  ((unsigned int)f2bf(acc[c + 1]) << 16);
                dst[c >> 1] = pk;
            }
        } else {
#pragma unroll
            for (int c = 0; c < FT; c++)
                hb[(size_t)n * 64 + fbase + c] = f2bf(acc[c]);
        }
    }

    __syncthreads();
    if (threadIdx.x < 64 && n < N) {
        float s = red[0][0][lane] + red[0][1][lane] + red[0][2][lane] + red[0][3][lane];
        float d = red[1][0][lane] + red[1][1][lane] + red[1][2][lane] + red[1][3][lane];
        asrc[n] = s;
        adst[n] = d;
    }
}

// -------------------- aggregation layer 1 (FOUT=48, relu, writes act1) ----------

#define CHUNK 128

template <int FOUT, bool RELU>
__global__ __launch_bounds__(256) void agg_bf16_kernel(
    const int* __restrict__ rowptr, const int* __restrict__ csr,
    const float* __restrict__ asrc, const float* __restrict__ adst,
    const unsigned short* __restrict__ hb, const float* __restrict__ bias,
    float* __restrict__ OUT, int N) {
    __shared__ int2 wslds[4][CHUNK];   // {src, w bits}
    const int wv = threadIdx.x >> 6;
    int n = blockIdx.x * 4 + wv;
    if (n >= N) return;
    const int lane = threadIdx.x & 63;
    const int rs = rowptr[n], re = rowptr[n + 1];
    const float ad_n = adst[n];
    const float wself = __expf(leaky(asrc[n] + ad_n));
    const int fc = (lane < FOUT) ? lane : FOUT - 1;  // clamp: dup load, never stored

    float acc = wself * bf2f(hb[(size_t)n * 64 + fc]);
    float wpart = 0.f;

    for (int base = rs; base < re; base += CHUNK) {
        const int cnt = min(CHUNK, re - base);
        if (lane < cnt) {
            int s = csr[base + lane];
            float w = __expf(leaky(asrc[s] + ad_n));
            wpart += w;
            wslds[wv][lane] = make_int2(s, __float_as_int(w));
        }
        int i = 0;
        for (; i + 8 <= cnt; i += 8) {
            int2 p[8];
#pragma unroll
            for (int u = 0; u < 8; u++) p[u] = wslds[wv][i + u];
            float hv[8];
#pragma unroll
            for (int u = 0; u < 8; u++) hv[u] = bf2f(hb[(size_t)p[u].x * 64 + fc]);
#pragma unroll
            for (int u = 0; u < 8; u++) acc = fmaf(__int_as_float(p[u].y), hv[u], acc);
        }
        for (; i < cnt; i++) {
            int2 pp = wslds[wv][i];
            acc = fmaf(__int_as_float(pp.y), bf2f(hb[(size_t)pp.x * 64 + fc]), acc);
        }
    }

#pragma unroll
    for (int off = 32; off; off >>= 1) wpart += __shfl_xor(wpart, off, 64);
    float ssum = wpart + wself;

    if (lane < FOUT) {
        float o = acc / (ssum + 1e-16f) + bias[lane];
        if (RELU) o = fmaxf(o, 0.f);
        OUT[(size_t)n * FOUT + lane] = o;
    }
}

// -------------------- aggregation layer 2 fused with layer-3 GEMM --------------------

__global__ __launch_bounds__(256) void agg_bf16_h3_kernel(
    const int* __restrict__ rowptr, const int* __restrict__ csr,
    const float* __restrict__ asrc, const float* __restrict__ adst,
    const unsigned short* __restrict__ hb, const float* __restrict__ bias,
    const float* __restrict__ W3, float* __restrict__ h3, int N) {
    constexpr int FOUT = 60;
    __shared__ int2 wslds[4][CHUNK];
    const int wv = threadIdx.x >> 6;
    int n = blockIdx.x * 4 + wv;
    if (n >= N) return;
    const int lane = threadIdx.x & 63;
    const int rs = rowptr[n], re = rowptr[n + 1];
    const float ad_n = adst[n];
    const float wself = __expf(leaky(asrc[n] + ad_n));
    const int fc = (lane < FOUT) ? lane : FOUT - 1;

    float acc = wself * bf2f(hb[(size_t)n * 64 + fc]);
    float wpart = 0.f;

    for (int base = rs; base < re; base += CHUNK) {
        const int cnt = min(CHUNK, re - base);
        if (lane < cnt) {
            int s = csr[base + lane];
            float w = __expf(leaky(asrc[s] + ad_n));
            wpart += w;
            wslds[wv][lane] = make_int2(s, __float_as_int(w));
        }
        int i = 0;
        for (; i + 8 <= cnt; i += 8) {
            int2 p[8];
#pragma unroll
            for (int u = 0; u < 8; u++) p[u] = wslds[wv][i + u];
            float hv[8];
#pragma unroll
            for (int u = 0; u < 8; u++) hv[u] = bf2f(hb[(size_t)p[u].x * 64 + fc]);
#pragma unroll
            for (int u = 0; u < 8; u++) acc = fmaf(__int_as_float(p[u].y), hv[u], acc);
        }
        for (; i < cnt; i++) {
            int2 pp = wslds[wv][i];
            acc = fmaf(__int_as_float(pp.y), bf2f(hb[(size_t)pp.x * 64 + fc]), acc);
        }
    }

#pragma unroll
    for (int off = 32; off; off >>= 1) wpart += __shfl_xor(wpart, off, 64);
    float ssum = wpart + wself;

    // act2[n,lane] = relu(acc/ssum + bias); fold layer-3 GEMM: t = act2 * W3
    float t = 0.f;
    if (lane < FOUT) {
        float o = fmaxf(acc / (ssum + 1e-16f) + bias[lane], 0.f);
        t = o * W3[lane];
    }
#pragma unroll
    for (int off = 32; off; off >>= 1) t += __shfl_xor(t, off, 64);
    if (lane == 0) h3[n] = t;
}

// -------------------- layer-3 aggregation: alpha derived from h3 --------------------

__global__ __launch_bounds__(256) void agg1_kernel(
    const int* __restrict__ rowptr, const int* __restrict__ csr,
    const float* __restrict__ h3,
    const float* __restrict__ as3p, const float* __restrict__ ad3p,
    const float* __restrict__ bias, float* __restrict__ OUT, int N) {
    int n = blockIdx.x * 4 + (threadIdx.x >> 6);
    if (n >= N) return;
    int lane = threadIdx.x & 63;
    int rs = rowptr[n], re = rowptr[n + 1];
    const float a_s = as3p[0];
    float hn = h3[n];
    float adn = ad3p[0] * hn;
    float wself = __expf(leaky(a_s * hn + adn));

    float ssum = 0.f, accv = 0.f;
    for (int e = rs + lane; e < re; e += 64) {
        float hs = h3[csr[e]];
        float w = __expf(leaky(a_s * hs + adn));
        ssum += w;
        accv = fmaf(w, hs, accv);
    }
#pragma unroll
    for (int off = 32; off; off >>= 1) {
        ssum += __shfl_xor(ssum, off, 64);
        accv += __shfl_xor(accv, off, 64);
    }
    ssum += wself;
    accv = fmaf(wself, hn, accv);
    if (lane == 0) OUT[n] = accv / (ssum + 1e-16f) + bias[0];
}

// -------------------- host launcher --------------------

extern "C" void kernel_launch(void* const* d_in, const int* in_sizes, int n_in,
                              void* d_out, int out_size, void* d_ws, size_t ws_size,
                              hipStream_t stream) {
    const float* x      = (const float*)d_in[0];
    const int*   ei     = (const int*)d_in[1];   // int32 per harness convention
    // d_in[2] = edge_attr: ignored by reference (no edge_dim)
    const float* W1  = (const float*)d_in[3];
    const float* as1 = (const float*)d_in[4];
    const float* ad1 = (const float*)d_in[5];
    const float* b1  = (const float*)d_in[6];
    const float* W2  = (const float*)d_in[7];
    const float* as2 = (const float*)d_in[8];
    const float* ad2 = (const float*)d_in[9];
    const float* b2  = (const float*)d_in[10];
    const float* W3  = (const float*)d_in[11];
    const float* as3 = (const float*)d_in[12];
    const float* ad3 = (const float*)d_in[13];
    const float* b3  = (const float*)d_in[14];

    const int N = in_sizes[0] / 256;   // 50000
    const int E = in_sizes[1] / 2;     // 1600000
    const int K = (N + (1 << BSHIFT) - 1) >> BSHIFT;   // 391 buckets

    char* p = (char*)d_ws;
    auto alloc = [&](size_t bytes) -> void* {
        void* r = (void*)p;
        p += ((bytes + 255) / 256) * 256;
        return r;
    };
    int*   gcursor = (int*)alloc(512 * 4);
    int*   bbase   = (int*)alloc(512 * 4);
    int*   rowptr  = (int*)alloc(((size_t)N + 1) * 4);
    int*   csr     = (int*)alloc((size_t)E * 4);
    unsigned short* hb = (unsigned short*)alloc((size_t)N * 64 * 2);  // bf16 H, 128B rows
    float* actbuf  = (float*)alloc((size_t)N * 48 * 4);               // act1 only
    float* h3      = (float*)alloc((size_t)N * 4);
    float* asrc    = (float*)alloc((size_t)N * 4);
    float* adst    = (float*)alloc((size_t)N * 4);
    // staged bucket regions (8 MB) alias actbuf (9.6 MB, dead until first agg):
    unsigned int* staged = (unsigned int*)actbuf;

    // ---- CSR build (two-level bucketed counting sort) ----
    hipMemsetAsync(gcursor, 0, 512 * 4, stream);
    int cblocks = (E + CTILE - 1) / CTILE;
    coarse_bin_kernel<<<cblocks, 256, 0, stream>>>(ei, staged, gcursor, E, K);
    bucket_scan_kernel<<<1, 512, 0, stream>>>(gcursor, bbase, K);
    fine_sort_kernel<<<K, 256, 0, stream>>>(staged, gcursor, bbase, rowptr, csr, N, E);

    int gblocks = (N + 63) / 64;       // 64 nodes per block (lane = node)
    int ablocks = (N + 3) / 4;

    // ---- layer 1: 256 -> 48, relu ----
    gemm_rl_kernel<256, 48, 12><<<gblocks, 256, 0, stream>>>(
        x, W1, as1, ad1, hb, asrc, adst, N);
    agg_bf16_kernel<48, true><<<ablocks, 256, 0, stream>>>(rowptr, csr, asrc, adst, hb, b1, actbuf, N);

    // ---- layer 2: 48 -> 60, relu, fused layer-3 GEMM in agg epilogue ----
    gemm_rl_kernel<48, 60, 15><<<gblocks, 256, 0, stream>>>(
        actbuf, W2, as2, ad2, hb, asrc, adst, N);
    agg_bf16_h3_kernel<<<ablocks, 256, 0, stream>>>(rowptr, csr, asrc, adst, hb, b2, W3, h3, N);

    // ---- layer 3 aggregation: straight to d_out ----
    agg1_kernel<<<ablocks, 256, 0, stream>>>(rowptr, csr, h3, as3, ad3, b3, (float*)d_out, N);
}

// Round 2
// 298.188 us; speedup vs baseline: 1.0223x; 1.0223x over previous
//
#include <hip/hip_runtime.h>
#include <cstdint>
#include <cstddef>

// ---------------------------------------------------------------------------
// GAT 3-layer forward, MI355X.
// Round 14: R13 (readlane W-broadcast) regressed 45->97us: VGPR=36 proves the
// compiler refused the 3k-instr full unroll, runtime-indexed xb/wreg went to
// scratch (rule #20). Revert to wave-uniform s_load W (R12 proved: no scratch,
// no LDS pipe), but SPLIT K ACROSS THE 4 WAVES instead of splitting FOUT:
// per k-step the s_load stall amortizes over 48 FMAs (was 12) and the serial
// chain is 64 steps (was 256); per-wave W working set 12KB fits scalar L1.
// Cross-wave k-reduce via LDS red[4][64][52] (stride 52 dw: 8 start banks x
// 4 dw = all 32 banks, conflict-optimal b128; 3 blocks/CU). Layer-2 GEMM
// (K=48, short chain) stays on the proven R12 gemm_sgpr structure.
// ---------------------------------------------------------------------------

__device__ __forceinline__ float leaky(float v) { return v > 0.f ? v : 0.2f * v; }

__device__ __forceinline__ unsigned short f2bf(float x) {
    unsigned int u = __float_as_uint(x);
    u = (u + 0x7FFFu + ((u >> 16) & 1u)) >> 16;   // RNE
    return (unsigned short)u;
}
__device__ __forceinline__ float bf2f(unsigned short b) {
    return __uint_as_float(((unsigned int)b) << 16);
}

#define BSHIFT 7                 // 128 nodes per bucket
#define BCAP   5120              // slots per bucket region (mean 4096, +16 sigma)
#define CTILE  8192              // edges per coarse block

// -------------------- coarse bin: edges -> bucket regions --------------------

__global__ __launch_bounds__(256) void coarse_bin_kernel(
    const int* __restrict__ ei, unsigned int* __restrict__ staged,
    int* __restrict__ gcursor, int E, int K) {
    __shared__ int hist[512];
    __shared__ int rank[512];
    __shared__ int base[512];
    for (int b = threadIdx.x; b < K; b += 256) { hist[b] = 0; rank[b] = 0; }
    __syncthreads();

    int e0 = blockIdx.x * CTILE;
    int e1 = min(E, e0 + CTILE);

    for (int e = e0 + threadIdx.x; e < e1; e += 256) {
        int d = ei[E + e];
        atomicAdd(&hist[d >> BSHIFT], 1);
    }
    __syncthreads();

    for (int b = threadIdx.x; b < K; b += 256) {
        int c = hist[b];
        base[b] = c ? atomicAdd(&gcursor[b], c) : 0;
    }
    __syncthreads();

    for (int e = e0 + threadIdx.x; e < e1; e += 256) {
        int s = ei[e];
        int d = ei[E + e];
        int b = d >> BSHIFT;
        int r = atomicAdd(&rank[b], 1);
        staged[(size_t)b * BCAP + base[b] + r] =
            ((unsigned int)(d & ((1 << BSHIFT) - 1)) << 16) | (unsigned int)s;
    }
}

// -------------------- bucket base scan (1 block) --------------------

__global__ __launch_bounds__(512) void bucket_scan_kernel(
    const int* __restrict__ gcursor, int* __restrict__ bbase, int K) {
    __shared__ int sh[512];
    int t = threadIdx.x;
    int v = (t < K) ? gcursor[t] : 0;
    sh[t] = v;
    __syncthreads();
    for (int off = 1; off < 512; off <<= 1) {
        int a = (t >= off) ? sh[t - off] : 0;
        __syncthreads();
        sh[t] += a;
        __syncthreads();
    }
    if (t < K) bbase[t] = sh[t] - v;   // exclusive
}

// -------------------- fine pass: bucket -> rowptr + sorted csr --------------------

__global__ __launch_bounds__(256) void fine_sort_kernel(
    const unsigned int* __restrict__ staged, const int* __restrict__ gcursor,
    const int* __restrict__ bbase, int* __restrict__ rowptr, int* __restrict__ csr,
    int N, int E) {
    __shared__ int cnt[128];
    __shared__ int off[128];
    __shared__ int lcsr[BCAP];
    const int b = blockIdx.x;
    const int t = threadIdx.x;
    const int c = gcursor[b];
    const int gb = bbase[b];
    const unsigned int* rec = staged + (size_t)b * BCAP;

    if (t < 128) cnt[t] = 0;
    __syncthreads();

    for (int i = t; i < c; i += 256) atomicAdd(&cnt[rec[i] >> 16], 1);
    __syncthreads();

    if (t < 128) off[t] = cnt[t];
    __syncthreads();
    for (int s = 1; s < 128; s <<= 1) {
        int a = (t >= s && t < 128) ? off[t - s] : 0;
        __syncthreads();
        if (t < 128) off[t] += a;
        __syncthreads();
    }

    if (t < 128) {
        int excl = off[t] - cnt[t];
        int n = (b << BSHIFT) + t;
        if (n <= N) rowptr[n] = gb + excl;
        cnt[t] = excl;
    }
    if (b == 0 && t == 0) rowptr[N] = E;
    __syncthreads();

    for (int i = t; i < c; i += 256) {
        unsigned int r = rec[i];
        int p = atomicAdd(&cnt[r >> 16], 1);
        lcsr[p] = (int)(r & 0xFFFFu);
    }
    __syncthreads();

    for (int i = t; i < c; i += 256) csr[gb + i] = lcsr[i];
}

// -------------------- layer-1 GEMM: K split across waves --------------------
// lane = node (64 nodes/block); wave wid covers k in [wid*K4, wid*K4+K4) and
// computes ALL FOUT columns. W rows read wave-uniform (s_load); per k-step the
// latency amortizes over FOUT=48 FMAs and the serial chain is only K4=64
// steps; per-wave W working set = K4*FOUT*4 = 12KB (fits scalar L1).
// Cross-wave reduce via LDS (padded stride 52 dw -> conflict-optimal b128),
// fused with alpha dot-products and bf16 h store.

template <int FIN, int FOUT>
__global__ __launch_bounds__(256) void gemm_ksplit_kernel(
    const float* __restrict__ X, const float* __restrict__ W,
    const float* __restrict__ avs, const float* __restrict__ avd,
    unsigned short* __restrict__ hb, float* __restrict__ asrc, float* __restrict__ adst,
    int N) {
    static_assert(FIN % 16 == 0, "FIN multiple of 16");
    static_assert(FOUT % 8 == 0, "FOUT multiple of 8 (b128 + dword bf16 packs)");
    constexpr int K4  = FIN / 4;
    constexpr int CPT = FOUT / 4;            // c-range per thread in reduce
    constexpr int PAD = 52;                  // stride: 52%32=20, gcd(20,32)=4 -> 8 start banks
    __shared__ float red[4][64][PAD];

    const int wid  = __builtin_amdgcn_readfirstlane(threadIdx.x >> 6); // 0..3
    const int lane = threadIdx.x & 63;
    const int n    = blockIdx.x * 64 + lane;
    const int nc   = (n < N) ? n : N - 1;    // clamp loads; stores guarded
    const float* xrow  = X + (size_t)nc * FIN + wid * K4;
    const float* wbase = W + (size_t)wid * K4 * FOUT;   // uniform

    float acc[FOUT];
#pragma unroll
    for (int c = 0; c < FOUT; c++) acc[c] = 0.f;

#pragma unroll
    for (int k = 0; k < K4; k += 4) {
        float4 xv = *(const float4*)(xrow + k);
        const float* w0 = wbase + (size_t)k * FOUT;     // uniform base
#pragma unroll
        for (int c = 0; c < FOUT; c++) {
            acc[c] = fmaf(xv.x, w0[c],            acc[c]);
            acc[c] = fmaf(xv.y, w0[FOUT + c],     acc[c]);
            acc[c] = fmaf(xv.z, w0[2 * FOUT + c], acc[c]);
            acc[c] = fmaf(xv.w, w0[3 * FOUT + c], acc[c]);
        }
    }

    // partials -> LDS (b128, conflict-optimal via PAD stride)
#pragma unroll
    for (int c = 0; c < FOUT; c += 4)
        *(float4*)&red[wid][lane][c] = make_float4(acc[c], acc[c + 1], acc[c + 2], acc[c + 3]);
    __syncthreads();

    // reduce: thread t -> node t>>2, c-range (t&3)*CPT
    {
        const int node = threadIdx.x >> 2;
        const int cg   = (threadIdx.x & 3) * CPT;
        const int gn   = blockIdx.x * 64 + node;
        float h[CPT];
#pragma unroll
        for (int c = 0; c < CPT; c++)
            h[c] = red[0][node][cg + c] + red[1][node][cg + c] +
                   red[2][node][cg + c] + red[3][node][cg + c];

        float ps = 0.f, pd = 0.f;
#pragma unroll
        for (int c = 0; c < CPT; c++) {
            ps = fmaf(h[c], avs[cg + c], ps);
            pd = fmaf(h[c], avd[cg + c], pd);
        }
        ps += __shfl_xor(ps, 1, 64); pd += __shfl_xor(pd, 1, 64);
        ps += __shfl_xor(ps, 2, 64); pd += __shfl_xor(pd, 2, 64);

        if (gn < N) {
            if ((threadIdx.x & 3) == 0) { asrc[gn] = ps; adst[gn] = pd; }
            // CPT even (FOUT%8==0) and cg even -> dword-aligned bf16 packs
            unsigned int* dst = (unsigned int*)(hb + (size_t)gn * 64 + cg);
#pragma unroll
            for (int c = 0; c < CPT; c += 2)
                dst[c >> 1] = (unsigned int)f2bf(h[c]) |
                              ((unsigned int)f2bf(h[c + 1]) << 16);
        }
    }
}

// -------------------- layer-2 GEMM (R12 structure: fout split, s_load W) ----

template <int FIN, int FOUT, int FT>
__global__ __launch_bounds__(256) void gemm_sgpr_kernel(
    const float* __restrict__ X, const float* __restrict__ W,
    const float* __restrict__ avs, const float* __restrict__ avd,
    unsigned short* __restrict__ hb, float* __restrict__ asrc, float* __restrict__ adst,
    int N) {
    static_assert(4 * FT == FOUT, "FT must be FOUT/4");
    __shared__ float red[2][4][64];

    const int wid  = __builtin_amdgcn_readfirstlane(threadIdx.x >> 6); // wave id 0..3
    const int lane = threadIdx.x & 63;
    const int n    = blockIdx.x * 64 + lane;
    const int nc   = (n < N) ? n : N - 1;     // clamp loads; stores guarded
    const int fbase = wid * FT;               // uniform

    const float* xrow = X + (size_t)nc * FIN;

    float acc[FT];
#pragma unroll
    for (int c = 0; c < FT; c++) acc[c] = 0.f;

#pragma unroll
    for (int k = 0; k < FIN; k += 4) {
        float4 xv = *(const float4*)(xrow + k);
        const float* w0 = W + (size_t)k * FOUT + fbase;   // uniform base
#pragma unroll
        for (int c = 0; c < FT; c++) {
            acc[c] = fmaf(xv.x, w0[c],            acc[c]);
            acc[c] = fmaf(xv.y, w0[FOUT + c],     acc[c]);
            acc[c] = fmaf(xv.z, w0[2 * FOUT + c], acc[c]);
            acc[c] = fmaf(xv.w, w0[3 * FOUT + c], acc[c]);
        }
    }

    // alpha partials over this wave's fout subset (avs/avd loads are uniform)
    float ps = 0.f, pd = 0.f;
#pragma unroll
    for (int c = 0; c < FT; c++) {
        ps = fmaf(acc[c], avs[fbase + c], ps);
        pd = fmaf(acc[c], avd[fbase + c], pd);
    }
    red[0][wid][lane] = ps;
    red[1][wid][lane] = pd;

    // h store (bf16, padded 64-entry rows)
    if (n < N) {
        if constexpr ((FT & 1) == 0) {
            unsigned int* dst = (unsigned int*)(hb + (size_t)n * 64 + fbase);
#pragma unroll
            for (int c = 0; c < FT; c += 2) {
                unsigned int pk = (unsigned int)f2bf(acc[c]) |
                                  ((unsigned int)f2bf(acc[c + 1]) << 16);
                dst[c >> 1] = pk;
            }
        } else {
#pragma unroll
            for (int c = 0; c < FT; c++)
                hb[(size_t)n * 64 + fbase + c] = f2bf(acc[c]);
        }
    }

    __syncthreads();
    if (threadIdx.x < 64 && n < N) {
        float s = red[0][0][lane] + red[0][1][lane] + red[0][2][lane] + red[0][3][lane];
        float d = red[1][0][lane] + red[1][1][lane] + red[1][2][lane] + red[1][3][lane];
        asrc[n] = s;
        adst[n] = d;
    }
}

// -------------------- aggregation layer 1 (FOUT=48, relu, writes act1) ----------

#define CHUNK 128

template <int FOUT, bool RELU>
__global__ __launch_bounds__(256) void agg_bf16_kernel(
    const int* __restrict__ rowptr, const int* __restrict__ csr,
    const float* __restrict__ asrc, const float* __restrict__ adst,
    const unsigned short* __restrict__ hb, const float* __restrict__ bias,
    float* __restrict__ OUT, int N) {
    __shared__ int2 wslds[4][CHUNK];   // {src, w bits}
    const int wv = threadIdx.x >> 6;
    int n = blockIdx.x * 4 + wv;
    if (n >= N) return;
    const int lane = threadIdx.x & 63;
    const int rs = rowptr[n], re = rowptr[n + 1];
    const float ad_n = adst[n];
    const float wself = __expf(leaky(asrc[n] + ad_n));
    const int fc = (lane < FOUT) ? lane : FOUT - 1;  // clamp: dup load, never stored

    float acc = wself * bf2f(hb[(size_t)n * 64 + fc]);
    float wpart = 0.f;

    for (int base = rs; base < re; base += CHUNK) {
        const int cnt = min(CHUNK, re - base);
        if (lane < cnt) {
            int s = csr[base + lane];
            float w = __expf(leaky(asrc[s] + ad_n));
            wpart += w;
            wslds[wv][lane] = make_int2(s, __float_as_int(w));
        }
        int i = 0;
        for (; i + 8 <= cnt; i += 8) {
            int2 p[8];
#pragma unroll
            for (int u = 0; u < 8; u++) p[u] = wslds[wv][i + u];
            float hv[8];
#pragma unroll
            for (int u = 0; u < 8; u++) hv[u] = bf2f(hb[(size_t)p[u].x * 64 + fc]);
#pragma unroll
            for (int u = 0; u < 8; u++) acc = fmaf(__int_as_float(p[u].y), hv[u], acc);
        }
        for (; i < cnt; i++) {
            int2 pp = wslds[wv][i];
            acc = fmaf(__int_as_float(pp.y), bf2f(hb[(size_t)pp.x * 64 + fc]), acc);
        }
    }

#pragma unroll
    for (int off = 32; off; off >>= 1) wpart += __shfl_xor(wpart, off, 64);
    float ssum = wpart + wself;

    if (lane < FOUT) {
        float o = acc / (ssum + 1e-16f) + bias[lane];
        if (RELU) o = fmaxf(o, 0.f);
        OUT[(size_t)n * FOUT + lane] = o;
    }
}

// -------------------- aggregation layer 2 fused with layer-3 GEMM --------------------

__global__ __launch_bounds__(256) void agg_bf16_h3_kernel(
    const int* __restrict__ rowptr, const int* __restrict__ csr,
    const float* __restrict__ asrc, const float* __restrict__ adst,
    const unsigned short* __restrict__ hb, const float* __restrict__ bias,
    const float* __restrict__ W3, float* __restrict__ h3, int N) {
    constexpr int FOUT = 60;
    __shared__ int2 wslds[4][CHUNK];
    const int wv = threadIdx.x >> 6;
    int n = blockIdx.x * 4 + wv;
    if (n >= N) return;
    const int lane = threadIdx.x & 63;
    const int rs = rowptr[n], re = rowptr[n + 1];
    const float ad_n = adst[n];
    const float wself = __expf(leaky(asrc[n] + ad_n));
    const int fc = (lane < FOUT) ? lane : FOUT - 1;

    float acc = wself * bf2f(hb[(size_t)n * 64 + fc]);
    float wpart = 0.f;

    for (int base = rs; base < re; base += CHUNK) {
        const int cnt = min(CHUNK, re - base);
        if (lane < cnt) {
            int s = csr[base + lane];
            float w = __expf(leaky(asrc[s] + ad_n));
            wpart += w;
            wslds[wv][lane] = make_int2(s, __float_as_int(w));
        }
        int i = 0;
        for (; i + 8 <= cnt; i += 8) {
            int2 p[8];
#pragma unroll
            for (int u = 0; u < 8; u++) p[u] = wslds[wv][i + u];
            float hv[8];
#pragma unroll
            for (int u = 0; u < 8; u++) hv[u] = bf2f(hb[(size_t)p[u].x * 64 + fc]);
#pragma unroll
            for (int u = 0; u < 8; u++) acc = fmaf(__int_as_float(p[u].y), hv[u], acc);
        }
        for (; i < cnt; i++) {
            int2 pp = wslds[wv][i];
            acc = fmaf(__int_as_float(pp.y), bf2f(hb[(size_t)pp.x * 64 + fc]), acc);
        }
    }

#pragma unroll
    for (int off = 32; off; off >>= 1) wpart += __shfl_xor(wpart, off, 64);
    float ssum = wpart + wself;

    // act2[n,lane] = relu(acc/ssum + bias); fold layer-3 GEMM: t = act2 * W3
    float t = 0.f;
    if (lane < FOUT) {
        float o = fmaxf(acc / (ssum + 1e-16f) + bias[lane], 0.f);
        t = o * W3[lane];
    }
#pragma unroll
    for (int off = 32; off; off >>= 1) t += __shfl_xor(t, off, 64);
    if (lane == 0) h3[n] = t;
}

// -------------------- layer-3 aggregation: alpha derived from h3 --------------------

__global__ __launch_bounds__(256) void agg1_kernel(
    const int* __restrict__ rowptr, const int* __restrict__ csr,
    const float* __restrict__ h3,
    const float* __restrict__ as3p, const float* __restrict__ ad3p,
    const float* __restrict__ bias, float* __restrict__ OUT, int N) {
    int n = blockIdx.x * 4 + (threadIdx.x >> 6);
    if (n >= N) return;
    int lane = threadIdx.x & 63;
    int rs = rowptr[n], re = rowptr[n + 1];
    const float a_s = as3p[0];
    float hn = h3[n];
    float adn = ad3p[0] * hn;
    float wself = __expf(leaky(a_s * hn + adn));

    float ssum = 0.f, accv = 0.f;
    for (int e = rs + lane; e < re; e += 64) {
        float hs = h3[csr[e]];
        float w = __expf(leaky(a_s * hs + adn));
        ssum += w;
        accv = fmaf(w, hs, accv);
    }
#pragma unroll
    for (int off = 32; off; off >>= 1) {
        ssum += __shfl_xor(ssum, off, 64);
        accv += __shfl_xor(accv, off, 64);
    }
    ssum += wself;
    accv = fmaf(wself, hn, accv);
    if (lane == 0) OUT[n] = accv / (ssum + 1e-16f) + bias[0];
}

// -------------------- host launcher --------------------

extern "C" void kernel_launch(void* const* d_in, const int* in_sizes, int n_in,
                              void* d_out, int out_size, void* d_ws, size_t ws_size,
                              hipStream_t stream) {
    const float* x      = (const float*)d_in[0];
    const int*   ei     = (const int*)d_in[1];   // int32 per harness convention
    // d_in[2] = edge_attr: ignored by reference (no edge_dim)
    const float* W1  = (const float*)d_in[3];
    const float* as1 = (const float*)d_in[4];
    const float* ad1 = (const float*)d_in[5];
    const float* b1  = (const float*)d_in[6];
    const float* W2  = (const float*)d_in[7];
    const float* as2 = (const float*)d_in[8];
    const float* ad2 = (const float*)d_in[9];
    const float* b2  = (const float*)d_in[10];
    const float* W3  = (const float*)d_in[11];
    const float* as3 = (const float*)d_in[12];
    const float* ad3 = (const float*)d_in[13];
    const float* b3  = (const float*)d_in[14];

    const int N = in_sizes[0] / 256;   // 50000
    const int E = in_sizes[1] / 2;     // 1600000
    const int K = (N + (1 << BSHIFT) - 1) >> BSHIFT;   // 391 buckets

    char* p = (char*)d_ws;
    auto alloc = [&](size_t bytes) -> void* {
        void* r = (void*)p;
        p += ((bytes + 255) / 256) * 256;
        return r;
    };
    int*   gcursor = (int*)alloc(512 * 4);
    int*   bbase   = (int*)alloc(512 * 4);
    int*   rowptr  = (int*)alloc(((size_t)N + 1) * 4);
    int*   csr     = (int*)alloc((size_t)E * 4);
    unsigned short* hb = (unsigned short*)alloc((size_t)N * 64 * 2);  // bf16 H, 128B rows
    float* actbuf  = (float*)alloc((size_t)N * 48 * 4);               // act1 only
    float* h3      = (float*)alloc((size_t)N * 4);
    float* asrc    = (float*)alloc((size_t)N * 4);
    float* adst    = (float*)alloc((size_t)N * 4);
    // staged bucket regions (8 MB) alias actbuf (9.6 MB, dead until first agg):
    unsigned int* staged = (unsigned int*)actbuf;

    // ---- CSR build (two-level bucketed counting sort) ----
    hipMemsetAsync(gcursor, 0, 512 * 4, stream);
    int cblocks = (E + CTILE - 1) / CTILE;
    coarse_bin_kernel<<<cblocks, 256, 0, stream>>>(ei, staged, gcursor, E, K);
    bucket_scan_kernel<<<1, 512, 0, stream>>>(gcursor, bbase, K);
    fine_sort_kernel<<<K, 256, 0, stream>>>(staged, gcursor, bbase, rowptr, csr, N, E);

    int gblocks = (N + 63) / 64;       // 64 nodes per block (lane = node)
    int ablocks = (N + 3) / 4;

    // ---- layer 1: 256 -> 48, relu ----
    gemm_ksplit_kernel<256, 48><<<gblocks, 256, 0, stream>>>(
        x, W1, as1, ad1, hb, asrc, adst, N);
    agg_bf16_kernel<48, true><<<ablocks, 256, 0, stream>>>(rowptr, csr, asrc, adst, hb, b1, actbuf, N);

    // ---- layer 2: 48 -> 60, relu, fused layer-3 GEMM in agg epilogue ----
    gemm_sgpr_kernel<48, 60, 15><<<gblocks, 256, 0, stream>>>(
        actbuf, W2, as2, ad2, hb, asrc, adst, N);
    agg_bf16_h3_kernel<<<ablocks, 256, 0, stream>>>(rowptr, csr, asrc, adst, hb, b2, W3, h3, N);

    // ---- layer 3 aggregation: straight to d_out ----
    agg1_kernel<<<ablocks, 256, 0, stream>>>(rowptr, csr, h3, as3, ad3, b3, (float*)d_out, N);
}

// Round 3
// 285.308 us; speedup vs baseline: 1.0685x; 1.0451x over previous
//
#include <hip/hip_runtime.h>
#include <cstdint>
#include <cstddef>

// ---------------------------------------------------------------------------
// GAT 3-layer forward, MI355X.
// Round 15: R12/R14 proved a ~45us floor for ANY W-via-scalar-pipe GEMM (48KB
// W per block streamed through 16KB sK$ = L2-latency chain; grid 782 blocks =
// 3 blocks/CU caps TLP). LDS pipe (R8-R11, 47us) and readlane (R13, scratch)
// also dead. Fix: MFMA k-loop with ZERO LDS / ZERO scalar loads. W lives in
// VGPRs as fp16 B-fragments (96 VGPRs total); X streams from global (2x
// dwordx4 per k-step, mandatory traffic). Full precision via fp16 hi/lo split
// of X (acc += Ah*B; acc += Al*B): W fp16 rel err 2^-12 << bf16-h 2^-9.
// Fragment-layout-safe by construction: A and B use the same (group,elem)->k
// bijection; hardware contracts position-vs-position, so result is exact for
// ANY consistent assignment. C/D map col=lane&15,row=(lane>>4)*4+reg (m89).
// ---------------------------------------------------------------------------

__device__ __forceinline__ float leaky(float v) { return v > 0.f ? v : 0.2f * v; }

__device__ __forceinline__ unsigned short f2bf(float x) {
    unsigned int u = __float_as_uint(x);
    u = (u + 0x7FFFu + ((u >> 16) & 1u)) >> 16;   // RNE
    return (unsigned short)u;
}
__device__ __forceinline__ float bf2f(unsigned short b) {
    return __uint_as_float(((unsigned int)b) << 16);
}

typedef _Float16 half8 __attribute__((ext_vector_type(8)));
typedef float f32x4 __attribute__((ext_vector_type(4)));

#define BSHIFT 7                 // 128 nodes per bucket
#define BCAP   5120              // slots per bucket region (mean 4096, +16 sigma)
#define CTILE  8192              // edges per coarse block

// -------------------- coarse bin: edges -> bucket regions --------------------

__global__ __launch_bounds__(256) void coarse_bin_kernel(
    const int* __restrict__ ei, unsigned int* __restrict__ staged,
    int* __restrict__ gcursor, int E, int K) {
    __shared__ int hist[512];
    __shared__ int rank[512];
    __shared__ int base[512];
    for (int b = threadIdx.x; b < K; b += 256) { hist[b] = 0; rank[b] = 0; }
    __syncthreads();

    int e0 = blockIdx.x * CTILE;
    int e1 = min(E, e0 + CTILE);

    for (int e = e0 + threadIdx.x; e < e1; e += 256) {
        int d = ei[E + e];
        atomicAdd(&hist[d >> BSHIFT], 1);
    }
    __syncthreads();

    for (int b = threadIdx.x; b < K; b += 256) {
        int c = hist[b];
        base[b] = c ? atomicAdd(&gcursor[b], c) : 0;
    }
    __syncthreads();

    for (int e = e0 + threadIdx.x; e < e1; e += 256) {
        int s = ei[e];
        int d = ei[E + e];
        int b = d >> BSHIFT;
        int r = atomicAdd(&rank[b], 1);
        staged[(size_t)b * BCAP + base[b] + r] =
            ((unsigned int)(d & ((1 << BSHIFT) - 1)) << 16) | (unsigned int)s;
    }
}

// -------------------- bucket base scan (1 block) --------------------

__global__ __launch_bounds__(512) void bucket_scan_kernel(
    const int* __restrict__ gcursor, int* __restrict__ bbase, int K) {
    __shared__ int sh[512];
    int t = threadIdx.x;
    int v = (t < K) ? gcursor[t] : 0;
    sh[t] = v;
    __syncthreads();
    for (int off = 1; off < 512; off <<= 1) {
        int a = (t >= off) ? sh[t - off] : 0;
        __syncthreads();
        sh[t] += a;
        __syncthreads();
    }
    if (t < K) bbase[t] = sh[t] - v;   // exclusive
}

// -------------------- fine pass: bucket -> rowptr + sorted csr --------------------

__global__ __launch_bounds__(256) void fine_sort_kernel(
    const unsigned int* __restrict__ staged, const int* __restrict__ gcursor,
    const int* __restrict__ bbase, int* __restrict__ rowptr, int* __restrict__ csr,
    int N, int E) {
    __shared__ int cnt[128];
    __shared__ int off[128];
    __shared__ int lcsr[BCAP];
    const int b = blockIdx.x;
    const int t = threadIdx.x;
    const int c = gcursor[b];
    const int gb = bbase[b];
    const unsigned int* rec = staged + (size_t)b * BCAP;

    if (t < 128) cnt[t] = 0;
    __syncthreads();

    for (int i = t; i < c; i += 256) atomicAdd(&cnt[rec[i] >> 16], 1);
    __syncthreads();

    if (t < 128) off[t] = cnt[t];
    __syncthreads();
    for (int s = 1; s < 128; s <<= 1) {
        int a = (t >= s && t < 128) ? off[t - s] : 0;
        __syncthreads();
        if (t < 128) off[t] += a;
        __syncthreads();
    }

    if (t < 128) {
        int excl = off[t] - cnt[t];
        int n = (b << BSHIFT) + t;
        if (n <= N) rowptr[n] = gb + excl;
        cnt[t] = excl;
    }
    if (b == 0 && t == 0) rowptr[N] = E;
    __syncthreads();

    for (int i = t; i < c; i += 256) {
        unsigned int r = rec[i];
        int p = atomicAdd(&cnt[r >> 16], 1);
        lcsr[p] = (int)(r & 0xFFFFu);
    }
    __syncthreads();

    for (int i = t; i < c; i += 256) csr[gb + i] = lcsr[i];
}

// -------------------- layer-1 GEMM: MFMA, W-in-VGPR fp16 --------------------
// Block = 64 nodes, 4 waves; wave w owns rows [blk*64+w*16, +16), all 48 fouts.
// A (X) fragment: lane (col=l&15 -> row, grp=l>>4): 8 consecutive f32 at
// k = kk*32 + grp*8, split into fp16 hi/lo. B (W) fragments preloaded to
// VGPRs: Bf[t][kk][j] = fp16(W[kk*32+grp*8+j][t*16+col]) -- same (grp,j)->k
// map as A, so contraction is exact for any hardware k-assignment.
// C/D: col = l&15 (fout), row = (l>>4)*4 + reg (node) [m89-verified].

template <int FIN>
__global__ __launch_bounds__(256) void gemm1_mfma_kernel(
    const float* __restrict__ X, const float* __restrict__ W,
    const float* __restrict__ avs, const float* __restrict__ avd,
    unsigned short* __restrict__ hb, float* __restrict__ asrc, float* __restrict__ adst,
    int N) {
    constexpr int FOUT = 48;
    constexpr int KK = FIN / 32;            // 8 k-steps
    static_assert(FIN % 32 == 0, "FIN multiple of 32");

    const int wid  = __builtin_amdgcn_readfirstlane(threadIdx.x >> 6);
    const int lane = threadIdx.x & 63;
    const int col  = lane & 15;             // A-row / D-col index
    const int grp  = lane >> 4;             // k-group
    const int wbase = blockIdx.x * 64 + wid * 16;

    // A-row pointer (clamped; stores are guarded separately)
    int arow = wbase + col;
    if (arow >= N) arow = N - 1;
    const float* xrow = X + (size_t)arow * FIN + grp * 8;

    // ---- B-fragment preload: 3 n-tiles x KK k-steps, fp16 (96 VGPRs) ----
    half8 Bf[3][KK];
#pragma unroll
    for (int t = 0; t < 3; t++) {
#pragma unroll
        for (int kk = 0; kk < KK; kk++) {
            const float* wp = W + (size_t)(kk * 32 + grp * 8) * FOUT + t * 16 + col;
#pragma unroll
            for (int j = 0; j < 8; j++)
                Bf[t][kk][j] = (_Float16)wp[(size_t)j * FOUT];
        }
    }

    f32x4 acc0 = {0.f, 0.f, 0.f, 0.f};
    f32x4 acc1 = {0.f, 0.f, 0.f, 0.f};
    f32x4 acc2 = {0.f, 0.f, 0.f, 0.f};

#pragma unroll
    for (int kk = 0; kk < KK; kk++) {
        float4 xa = *(const float4*)(xrow + kk * 32);
        float4 xb = *(const float4*)(xrow + kk * 32 + 4);
        float xs[8] = {xa.x, xa.y, xa.z, xa.w, xb.x, xb.y, xb.z, xb.w};
        half8 ah, al;
#pragma unroll
        for (int j = 0; j < 8; j++) {
            _Float16 h = (_Float16)xs[j];
            ah[j] = h;
            al[j] = (_Float16)(xs[j] - (float)h);   // exact residual -> fp16
        }
        acc0 = __builtin_amdgcn_mfma_f32_16x16x32_f16(ah, Bf[0][kk], acc0, 0, 0, 0);
        acc1 = __builtin_amdgcn_mfma_f32_16x16x32_f16(ah, Bf[1][kk], acc1, 0, 0, 0);
        acc2 = __builtin_amdgcn_mfma_f32_16x16x32_f16(ah, Bf[2][kk], acc2, 0, 0, 0);
        acc0 = __builtin_amdgcn_mfma_f32_16x16x32_f16(al, Bf[0][kk], acc0, 0, 0, 0);
        acc1 = __builtin_amdgcn_mfma_f32_16x16x32_f16(al, Bf[1][kk], acc1, 0, 0, 0);
        acc2 = __builtin_amdgcn_mfma_f32_16x16x32_f16(al, Bf[2][kk], acc2, 0, 0, 0);
    }

    // ---- alpha partials: lane holds fout col of nodes wbase+grp*4+r ----
    float avs0 = avs[col], avs1 = avs[16 + col], avs2 = avs[32 + col];
    float avd0 = avd[col], avd1 = avd[16 + col], avd2 = avd[32 + col];

#pragma unroll
    for (int r = 0; r < 4; r++) {
        float ps = acc0[r] * avs0 + acc1[r] * avs1 + acc2[r] * avs2;
        float pd = acc0[r] * avd0 + acc1[r] * avd1 + acc2[r] * avd2;
#pragma unroll
        for (int off = 8; off; off >>= 1) {
            ps += __shfl_xor(ps, off, 64);
            pd += __shfl_xor(pd, off, 64);
        }
        int nd = wbase + grp * 4 + r;
        if (col == r && nd < N) { asrc[nd] = ps; adst[nd] = pd; }
    }

    // ---- h store (bf16, 64-entry padded rows) ----
#pragma unroll
    for (int r = 0; r < 4; r++) {
        int nd = wbase + grp * 4 + r;
        if (nd < N) {
            unsigned short* hp = hb + (size_t)nd * 64 + col;
            hp[0]  = f2bf(acc0[r]);
            hp[16] = f2bf(acc1[r]);
            hp[32] = f2bf(acc2[r]);
        }
    }
}

// -------------------- layer-2 GEMM (R12 structure: fout split, s_load W) ----

template <int FIN, int FOUT, int FT>
__global__ __launch_bounds__(256) void gemm_sgpr_kernel(
    const float* __restrict__ X, const float* __restrict__ W,
    const float* __restrict__ avs, const float* __restrict__ avd,
    unsigned short* __restrict__ hb, float* __restrict__ asrc, float* __restrict__ adst,
    int N) {
    static_assert(4 * FT == FOUT, "FT must be FOUT/4");
    __shared__ float red[2][4][64];

    const int wid  = __builtin_amdgcn_readfirstlane(threadIdx.x >> 6); // wave id 0..3
    const int lane = threadIdx.x & 63;
    const int n    = blockIdx.x * 64 + lane;
    const int nc   = (n < N) ? n : N - 1;     // clamp loads; stores guarded
    const int fbase = wid * FT;               // uniform

    const float* xrow = X + (size_t)nc * FIN;

    float acc[FT];
#pragma unroll
    for (int c = 0; c < FT; c++) acc[c] = 0.f;

#pragma unroll
    for (int k = 0; k < FIN; k += 4) {
        float4 xv = *(const float4*)(xrow + k);
        const float* w0 = W + (size_t)k * FOUT + fbase;   // uniform base
#pragma unroll
        for (int c = 0; c < FT; c++) {
            acc[c] = fmaf(xv.x, w0[c],            acc[c]);
            acc[c] = fmaf(xv.y, w0[FOUT + c],     acc[c]);
            acc[c] = fmaf(xv.z, w0[2 * FOUT + c], acc[c]);
            acc[c] = fmaf(xv.w, w0[3 * FOUT + c], acc[c]);
        }
    }

    // alpha partials over this wave's fout subset (avs/avd loads are uniform)
    float ps = 0.f, pd = 0.f;
#pragma unroll
    for (int c = 0; c < FT; c++) {
        ps = fmaf(acc[c], avs[fbase + c], ps);
        pd = fmaf(acc[c], avd[fbase + c], pd);
    }
    red[0][wid][lane] = ps;
    red[1][wid][lane] = pd;

    // h store (bf16, padded 64-entry rows)
    if (n < N) {
        if constexpr ((FT & 1) == 0) {
            unsigned int* dst = (unsigned int*)(hb + (size_t)n * 64 + fbase);
#pragma unroll
            for (int c = 0; c < FT; c += 2) {
                unsigned int pk = (unsigned int)f2bf(acc[c]) |
                                  ((unsigned int)f2bf(acc[c + 1]) << 16);
                dst[c >> 1] = pk;
            }
        } else {
#pragma unroll
            for (int c = 0; c < FT; c++)
                hb[(size_t)n * 64 + fbase + c] = f2bf(acc[c]);
        }
    }

    __syncthreads();
    if (threadIdx.x < 64 && n < N) {
        float s = red[0][0][lane] + red[0][1][lane] + red[0][2][lane] + red[0][3][lane];
        float d = red[1][0][lane] + red[1][1][lane] + red[1][2][lane] + red[1][3][lane];
        asrc[n] = s;
        adst[n] = d;
    }
}

// -------------------- aggregation layer 1 (FOUT=48, relu, writes act1) ----------

#define CHUNK 128

template <int FOUT, bool RELU>
__global__ __launch_bounds__(256) void agg_bf16_kernel(
    const int* __restrict__ rowptr, const int* __restrict__ csr,
    const float* __restrict__ asrc, const float* __restrict__ adst,
    const unsigned short* __restrict__ hb, const float* __restrict__ bias,
    float* __restrict__ OUT, int N) {
    __shared__ int2 wslds[4][CHUNK];   // {src, w bits}
    const int wv = threadIdx.x >> 6;
    int n = blockIdx.x * 4 + wv;
    if (n >= N) return;
    const int lane = threadIdx.x & 63;
    const int rs = rowptr[n], re = rowptr[n + 1];
    const float ad_n = adst[n];
    const float wself = __expf(leaky(asrc[n] + ad_n));
    const int fc = (lane < FOUT) ? lane : FOUT - 1;  // clamp: dup load, never stored

    float acc = wself * bf2f(hb[(size_t)n * 64 + fc]);
    float wpart = 0.f;

    for (int base = rs; base < re; base += CHUNK) {
        const int cnt = min(CHUNK, re - base);
        if (lane < cnt) {
            int s = csr[base + lane];
            float w = __expf(leaky(asrc[s] + ad_n));
            wpart += w;
            wslds[wv][lane] = make_int2(s, __float_as_int(w));
        }
        int i = 0;
        for (; i + 8 <= cnt; i += 8) {
            int2 p[8];
#pragma unroll
            for (int u = 0; u < 8; u++) p[u] = wslds[wv][i + u];
            float hv[8];
#pragma unroll
            for (int u = 0; u < 8; u++) hv[u] = bf2f(hb[(size_t)p[u].x * 64 + fc]);
#pragma unroll
            for (int u = 0; u < 8; u++) acc = fmaf(__int_as_float(p[u].y), hv[u], acc);
        }
        for (; i < cnt; i++) {
            int2 pp = wslds[wv][i];
            acc = fmaf(__int_as_float(pp.y), bf2f(hb[(size_t)pp.x * 64 + fc]), acc);
        }
    }

#pragma unroll
    for (int off = 32; off; off >>= 1) wpart += __shfl_xor(wpart, off, 64);
    float ssum = wpart + wself;

    if (lane < FOUT) {
        float o = acc / (ssum + 1e-16f) + bias[lane];
        if (RELU) o = fmaxf(o, 0.f);
        OUT[(size_t)n * FOUT + lane] = o;
    }
}

// -------------------- aggregation layer 2 fused with layer-3 GEMM --------------------

__global__ __launch_bounds__(256) void agg_bf16_h3_kernel(
    const int* __restrict__ rowptr, const int* __restrict__ csr,
    const float* __restrict__ asrc, const float* __restrict__ adst,
    const unsigned short* __restrict__ hb, const float* __restrict__ bias,
    const float* __restrict__ W3, float* __restrict__ h3, int N) {
    constexpr int FOUT = 60;
    __shared__ int2 wslds[4][CHUNK];
    const int wv = threadIdx.x >> 6;
    int n = blockIdx.x * 4 + wv;
    if (n >= N) return;
    const int lane = threadIdx.x & 63;
    const int rs = rowptr[n], re = rowptr[n + 1];
    const float ad_n = adst[n];
    const float wself = __expf(leaky(asrc[n] + ad_n));
    const int fc = (lane < FOUT) ? lane : FOUT - 1;

    float acc = wself * bf2f(hb[(size_t)n * 64 + fc]);
    float wpart = 0.f;

    for (int base = rs; base < re; base += CHUNK) {
        const int cnt = min(CHUNK, re - base);
        if (lane < cnt) {
            int s = csr[base + lane];
            float w = __expf(leaky(asrc[s] + ad_n));
            wpart += w;
            wslds[wv][lane] = make_int2(s, __float_as_int(w));
        }
        int i = 0;
        for (; i + 8 <= cnt; i += 8) {
            int2 p[8];
#pragma unroll
            for (int u = 0; u < 8; u++) p[u] = wslds[wv][i + u];
            float hv[8];
#pragma unroll
            for (int u = 0; u < 8; u++) hv[u] = bf2f(hb[(size_t)p[u].x * 64 + fc]);
#pragma unroll
            for (int u = 0; u < 8; u++) acc = fmaf(__int_as_float(p[u].y), hv[u], acc);
        }
        for (; i < cnt; i++) {
            int2 pp = wslds[wv][i];
            acc = fmaf(__int_as_float(pp.y), bf2f(hb[(size_t)pp.x * 64 + fc]), acc);
        }
    }

#pragma unroll
    for (int off = 32; off; off >>= 1) wpart += __shfl_xor(wpart, off, 64);
    float ssum = wpart + wself;

    // act2[n,lane] = relu(acc/ssum + bias); fold layer-3 GEMM: t = act2 * W3
    float t = 0.f;
    if (lane < FOUT) {
        float o = fmaxf(acc / (ssum + 1e-16f) + bias[lane], 0.f);
        t = o * W3[lane];
    }
#pragma unroll
    for (int off = 32; off; off >>= 1) t += __shfl_xor(t, off, 64);
    if (lane == 0) h3[n] = t;
}

// -------------------- layer-3 aggregation: alpha derived from h3 --------------------

__global__ __launch_bounds__(256) void agg1_kernel(
    const int* __restrict__ rowptr, const int* __restrict__ csr,
    const float* __restrict__ h3,
    const float* __restrict__ as3p, const float* __restrict__ ad3p,
    const float* __restrict__ bias, float* __restrict__ OUT, int N) {
    int n = blockIdx.x * 4 + (threadIdx.x >> 6);
    if (n >= N) return;
    int lane = threadIdx.x & 63;
    int rs = rowptr[n], re = rowptr[n + 1];
    const float a_s = as3p[0];
    float hn = h3[n];
    float adn = ad3p[0] * hn;
    float wself = __expf(leaky(a_s * hn + adn));

    float ssum = 0.f, accv = 0.f;
    for (int e = rs + lane; e < re; e += 64) {
        float hs = h3[csr[e]];
        float w = __expf(leaky(a_s * hs + adn));
        ssum += w;
        accv = fmaf(w, hs, accv);
    }
#pragma unroll
    for (int off = 32; off; off >>= 1) {
        ssum += __shfl_xor(ssum, off, 64);
        accv += __shfl_xor(accv, off, 64);
    }
    ssum += wself;
    accv = fmaf(wself, hn, accv);
    if (lane == 0) OUT[n] = accv / (ssum + 1e-16f) + bias[0];
}

// -------------------- host launcher --------------------

extern "C" void kernel_launch(void* const* d_in, const int* in_sizes, int n_in,
                              void* d_out, int out_size, void* d_ws, size_t ws_size,
                              hipStream_t stream) {
    const float* x      = (const float*)d_in[0];
    const int*   ei     = (const int*)d_in[1];   // int32 per harness convention
    // d_in[2] = edge_attr: ignored by reference (no edge_dim)
    const float* W1  = (const float*)d_in[3];
    const float* as1 = (const float*)d_in[4];
    const float* ad1 = (const float*)d_in[5];
    const float* b1  = (const float*)d_in[6];
    const float* W2  = (const float*)d_in[7];
    const float* as2 = (const float*)d_in[8];
    const float* ad2 = (const float*)d_in[9];
    const float* b2  = (const float*)d_in[10];
    const float* W3  = (const float*)d_in[11];
    const float* as3 = (const float*)d_in[12];
    const float* ad3 = (const float*)d_in[13];
    const float* b3  = (const float*)d_in[14];

    const int N = in_sizes[0] / 256;   // 50000
    const int E = in_sizes[1] / 2;     // 1600000
    const int K = (N + (1 << BSHIFT) - 1) >> BSHIFT;   // 391 buckets

    char* p = (char*)d_ws;
    auto alloc = [&](size_t bytes) -> void* {
        void* r = (void*)p;
        p += ((bytes + 255) / 256) * 256;
        return r;
    };
    int*   gcursor = (int*)alloc(512 * 4);
    int*   bbase   = (int*)alloc(512 * 4);
    int*   rowptr  = (int*)alloc(((size_t)N + 1) * 4);
    int*   csr     = (int*)alloc((size_t)E * 4);
    unsigned short* hb = (unsigned short*)alloc((size_t)N * 64 * 2);  // bf16 H, 128B rows
    float* actbuf  = (float*)alloc((size_t)N * 48 * 4);               // act1 only
    float* h3      = (float*)alloc((size_t)N * 4);
    float* asrc    = (float*)alloc((size_t)N * 4);
    float* adst    = (float*)alloc((size_t)N * 4);
    // staged bucket regions (8 MB) alias actbuf (9.6 MB, dead until first agg):
    unsigned int* staged = (unsigned int*)actbuf;

    // ---- CSR build (two-level bucketed counting sort) ----
    hipMemsetAsync(gcursor, 0, 512 * 4, stream);
    int cblocks = (E + CTILE - 1) / CTILE;
    coarse_bin_kernel<<<cblocks, 256, 0, stream>>>(ei, staged, gcursor, E, K);
    bucket_scan_kernel<<<1, 512, 0, stream>>>(gcursor, bbase, K);
    fine_sort_kernel<<<K, 256, 0, stream>>>(staged, gcursor, bbase, rowptr, csr, N, E);

    int gblocks = (N + 63) / 64;       // 64 nodes per block (lane = node)
    int ablocks = (N + 3) / 4;

    // ---- layer 1: 256 -> 48, relu (MFMA, W-in-VGPR fp16) ----
    gemm1_mfma_kernel<256><<<gblocks, 256, 0, stream>>>(
        x, W1, as1, ad1, hb, asrc, adst, N);
    agg_bf16_kernel<48, true><<<ablocks, 256, 0, stream>>>(rowptr, csr, asrc, adst, hb, b1, actbuf, N);

    // ---- layer 2: 48 -> 60, relu, fused layer-3 GEMM in agg epilogue ----
    gemm_sgpr_kernel<48, 60, 15><<<gblocks, 256, 0, stream>>>(
        actbuf, W2, as2, ad2, hb, asrc, adst, N);
    agg_bf16_h3_kernel<<<ablocks, 256, 0, stream>>>(rowptr, csr, asrc, adst, hb, b2, W3, h3, N);

    // ---- layer 3 aggregation: straight to d_out ----
    agg1_kernel<<<ablocks, 256, 0, stream>>>(rowptr, csr, h3, as3, ad3, b3, (float*)d_out, N);
}

// Round 4
// 283.578 us; speedup vs baseline: 1.0750x; 1.0061x over previous
//
#include <hip/hip_runtime.h>
#include <cstdint>
#include <cstddef>

// ---------------------------------------------------------------------------
// GAT 3-layer forward, MI355X.
// Round 16: gemm1 MFMA (R15) dropped off the profile top; the two edge-gather
// agg kernels (~42us each) are now the bottleneck: VALU-issue-bound at ~16
// cyc/edge (7 wave-issues per edge, 64 lanes fetching only 128B). New agg:
// 4 edges per iteration -- wave split into 4 quarters, quarter q handles edge
// i+q; lane (sub=lane&15) covers cols 4sub..4sub+3 via ONE global_load_dwordx2
// (saddr + 32-bit voffset; edge byte offset s<<7 staged in LDS so per-edge
// addr math is a single v_add_u32). ~2.75 issues/edge vs ~7. Quarter partials
// combined with shfl_xor(16|32); self term added post-combine; odd tails get
// w=0 on excess quarters. Everything else unchanged from R15.
// ---------------------------------------------------------------------------

__device__ __forceinline__ float leaky(float v) { return v > 0.f ? v : 0.2f * v; }

__device__ __forceinline__ unsigned short f2bf(float x) {
    unsigned int u = __float_as_uint(x);
    u = (u + 0x7FFFu + ((u >> 16) & 1u)) >> 16;   // RNE
    return (unsigned short)u;
}
__device__ __forceinline__ float bf2f(unsigned short b) {
    return __uint_as_float(((unsigned int)b) << 16);
}
__device__ __forceinline__ float bfhi(unsigned int d) {       // high bf16 of dword
    return __uint_as_float(d & 0xFFFF0000u);
}
__device__ __forceinline__ float bflo(unsigned int d) {       // low bf16 of dword
    return __uint_as_float(d << 16);
}

typedef _Float16 half8 __attribute__((ext_vector_type(8)));
typedef float f32x4 __attribute__((ext_vector_type(4)));

#define BSHIFT 7                 // 128 nodes per bucket
#define BCAP   5120              // slots per bucket region (mean 4096, +16 sigma)
#define CTILE  8192              // edges per coarse block

// -------------------- coarse bin: edges -> bucket regions --------------------

__global__ __launch_bounds__(256) void coarse_bin_kernel(
    const int* __restrict__ ei, unsigned int* __restrict__ staged,
    int* __restrict__ gcursor, int E, int K) {
    __shared__ int hist[512];
    __shared__ int rank[512];
    __shared__ int base[512];
    for (int b = threadIdx.x; b < K; b += 256) { hist[b] = 0; rank[b] = 0; }
    __syncthreads();

    int e0 = blockIdx.x * CTILE;
    int e1 = min(E, e0 + CTILE);

    for (int e = e0 + threadIdx.x; e < e1; e += 256) {
        int d = ei[E + e];
        atomicAdd(&hist[d >> BSHIFT], 1);
    }
    __syncthreads();

    for (int b = threadIdx.x; b < K; b += 256) {
        int c = hist[b];
        base[b] = c ? atomicAdd(&gcursor[b], c) : 0;
    }
    __syncthreads();

    for (int e = e0 + threadIdx.x; e < e1; e += 256) {
        int s = ei[e];
        int d = ei[E + e];
        int b = d >> BSHIFT;
        int r = atomicAdd(&rank[b], 1);
        staged[(size_t)b * BCAP + base[b] + r] =
            ((unsigned int)(d & ((1 << BSHIFT) - 1)) << 16) | (unsigned int)s;
    }
}

// -------------------- bucket base scan (1 block) --------------------

__global__ __launch_bounds__(512) void bucket_scan_kernel(
    const int* __restrict__ gcursor, int* __restrict__ bbase, int K) {
    __shared__ int sh[512];
    int t = threadIdx.x;
    int v = (t < K) ? gcursor[t] : 0;
    sh[t] = v;
    __syncthreads();
    for (int off = 1; off < 512; off <<= 1) {
        int a = (t >= off) ? sh[t - off] : 0;
        __syncthreads();
        sh[t] += a;
        __syncthreads();
    }
    if (t < K) bbase[t] = sh[t] - v;   // exclusive
}

// -------------------- fine pass: bucket -> rowptr + sorted csr --------------------

__global__ __launch_bounds__(256) void fine_sort_kernel(
    const unsigned int* __restrict__ staged, const int* __restrict__ gcursor,
    const int* __restrict__ bbase, int* __restrict__ rowptr, int* __restrict__ csr,
    int N, int E) {
    __shared__ int cnt[128];
    __shared__ int off[128];
    __shared__ int lcsr[BCAP];
    const int b = blockIdx.x;
    const int t = threadIdx.x;
    const int c = gcursor[b];
    const int gb = bbase[b];
    const unsigned int* rec = staged + (size_t)b * BCAP;

    if (t < 128) cnt[t] = 0;
    __syncthreads();

    for (int i = t; i < c; i += 256) atomicAdd(&cnt[rec[i] >> 16], 1);
    __syncthreads();

    if (t < 128) off[t] = cnt[t];
    __syncthreads();
    for (int s = 1; s < 128; s <<= 1) {
        int a = (t >= s && t < 128) ? off[t - s] : 0;
        __syncthreads();
        if (t < 128) off[t] += a;
        __syncthreads();
    }

    if (t < 128) {
        int excl = off[t] - cnt[t];
        int n = (b << BSHIFT) + t;
        if (n <= N) rowptr[n] = gb + excl;
        cnt[t] = excl;
    }
    if (b == 0 && t == 0) rowptr[N] = E;
    __syncthreads();

    for (int i = t; i < c; i += 256) {
        unsigned int r = rec[i];
        int p = atomicAdd(&cnt[r >> 16], 1);
        lcsr[p] = (int)(r & 0xFFFFu);
    }
    __syncthreads();

    for (int i = t; i < c; i += 256) csr[gb + i] = lcsr[i];
}

// -------------------- layer-1 GEMM: MFMA, W-in-VGPR fp16 (R15) --------------------

template <int FIN>
__global__ __launch_bounds__(256) void gemm1_mfma_kernel(
    const float* __restrict__ X, const float* __restrict__ W,
    const float* __restrict__ avs, const float* __restrict__ avd,
    unsigned short* __restrict__ hb, float* __restrict__ asrc, float* __restrict__ adst,
    int N) {
    constexpr int FOUT = 48;
    constexpr int KK = FIN / 32;            // 8 k-steps
    static_assert(FIN % 32 == 0, "FIN multiple of 32");

    const int wid  = __builtin_amdgcn_readfirstlane(threadIdx.x >> 6);
    const int lane = threadIdx.x & 63;
    const int col  = lane & 15;             // A-row / D-col index
    const int grp  = lane >> 4;             // k-group
    const int wbase = blockIdx.x * 64 + wid * 16;

    int arow = wbase + col;
    if (arow >= N) arow = N - 1;
    const float* xrow = X + (size_t)arow * FIN + grp * 8;

    // ---- B-fragment preload: 3 n-tiles x KK k-steps, fp16 (96 VGPRs) ----
    half8 Bf[3][KK];
#pragma unroll
    for (int t = 0; t < 3; t++) {
#pragma unroll
        for (int kk = 0; kk < KK; kk++) {
            const float* wp = W + (size_t)(kk * 32 + grp * 8) * FOUT + t * 16 + col;
#pragma unroll
            for (int j = 0; j < 8; j++)
                Bf[t][kk][j] = (_Float16)wp[(size_t)j * FOUT];
        }
    }

    f32x4 acc0 = {0.f, 0.f, 0.f, 0.f};
    f32x4 acc1 = {0.f, 0.f, 0.f, 0.f};
    f32x4 acc2 = {0.f, 0.f, 0.f, 0.f};

#pragma unroll
    for (int kk = 0; kk < KK; kk++) {
        float4 xa = *(const float4*)(xrow + kk * 32);
        float4 xb = *(const float4*)(xrow + kk * 32 + 4);
        float xs[8] = {xa.x, xa.y, xa.z, xa.w, xb.x, xb.y, xb.z, xb.w};
        half8 ah, al;
#pragma unroll
        for (int j = 0; j < 8; j++) {
            _Float16 h = (_Float16)xs[j];
            ah[j] = h;
            al[j] = (_Float16)(xs[j] - (float)h);   // exact residual -> fp16
        }
        acc0 = __builtin_amdgcn_mfma_f32_16x16x32_f16(ah, Bf[0][kk], acc0, 0, 0, 0);
        acc1 = __builtin_amdgcn_mfma_f32_16x16x32_f16(ah, Bf[1][kk], acc1, 0, 0, 0);
        acc2 = __builtin_amdgcn_mfma_f32_16x16x32_f16(ah, Bf[2][kk], acc2, 0, 0, 0);
        acc0 = __builtin_amdgcn_mfma_f32_16x16x32_f16(al, Bf[0][kk], acc0, 0, 0, 0);
        acc1 = __builtin_amdgcn_mfma_f32_16x16x32_f16(al, Bf[1][kk], acc1, 0, 0, 0);
        acc2 = __builtin_amdgcn_mfma_f32_16x16x32_f16(al, Bf[2][kk], acc2, 0, 0, 0);
    }

    // ---- alpha partials: lane holds fout col of nodes wbase+grp*4+r ----
    float avs0 = avs[col], avs1 = avs[16 + col], avs2 = avs[32 + col];
    float avd0 = avd[col], avd1 = avd[16 + col], avd2 = avd[32 + col];

#pragma unroll
    for (int r = 0; r < 4; r++) {
        float ps = acc0[r] * avs0 + acc1[r] * avs1 + acc2[r] * avs2;
        float pd = acc0[r] * avd0 + acc1[r] * avd1 + acc2[r] * avd2;
#pragma unroll
        for (int off = 8; off; off >>= 1) {
            ps += __shfl_xor(ps, off, 64);
            pd += __shfl_xor(pd, off, 64);
        }
        int nd = wbase + grp * 4 + r;
        if (col == r && nd < N) { asrc[nd] = ps; adst[nd] = pd; }
    }

    // ---- h store (bf16, 64-entry padded rows) ----
#pragma unroll
    for (int r = 0; r < 4; r++) {
        int nd = wbase + grp * 4 + r;
        if (nd < N) {
            unsigned short* hp = hb + (size_t)nd * 64 + col;
            hp[0]  = f2bf(acc0[r]);
            hp[16] = f2bf(acc1[r]);
            hp[32] = f2bf(acc2[r]);
        }
    }
}

// -------------------- layer-2 GEMM (R12 structure: fout split, s_load W) ----

template <int FIN, int FOUT, int FT>
__global__ __launch_bounds__(256) void gemm_sgpr_kernel(
    const float* __restrict__ X, const float* __restrict__ W,
    const float* __restrict__ avs, const float* __restrict__ avd,
    unsigned short* __restrict__ hb, float* __restrict__ asrc, float* __restrict__ adst,
    int N) {
    static_assert(4 * FT == FOUT, "FT must be FOUT/4");
    __shared__ float red[2][4][64];

    const int wid  = __builtin_amdgcn_readfirstlane(threadIdx.x >> 6); // wave id 0..3
    const int lane = threadIdx.x & 63;
    const int n    = blockIdx.x * 64 + lane;
    const int nc   = (n < N) ? n : N - 1;     // clamp loads; stores guarded
    const int fbase = wid * FT;               // uniform

    const float* xrow = X + (size_t)nc * FIN;

    float acc[FT];
#pragma unroll
    for (int c = 0; c < FT; c++) acc[c] = 0.f;

#pragma unroll
    for (int k = 0; k < FIN; k += 4) {
        float4 xv = *(const float4*)(xrow + k);
        const float* w0 = W + (size_t)k * FOUT + fbase;   // uniform base
#pragma unroll
        for (int c = 0; c < FT; c++) {
            acc[c] = fmaf(xv.x, w0[c],            acc[c]);
            acc[c] = fmaf(xv.y, w0[FOUT + c],     acc[c]);
            acc[c] = fmaf(xv.z, w0[2 * FOUT + c], acc[c]);
            acc[c] = fmaf(xv.w, w0[3 * FOUT + c], acc[c]);
        }
    }

    // alpha partials over this wave's fout subset (avs/avd loads are uniform)
    float ps = 0.f, pd = 0.f;
#pragma unroll
    for (int c = 0; c < FT; c++) {
        ps = fmaf(acc[c], avs[fbase + c], ps);
        pd = fmaf(acc[c], avd[fbase + c], pd);
    }
    red[0][wid][lane] = ps;
    red[1][wid][lane] = pd;

    // h store (bf16, padded 64-entry rows)
    if (n < N) {
        if constexpr ((FT & 1) == 0) {
            unsigned int* dst = (unsigned int*)(hb + (size_t)n * 64 + fbase);
#pragma unroll
            for (int c = 0; c < FT; c += 2) {
                unsigned int pk = (unsigned int)f2bf(acc[c]) |
                                  ((unsigned int)f2bf(acc[c + 1]) << 16);
                dst[c >> 1] = pk;
            }
        } else {
#pragma unroll
            for (int c = 0; c < FT; c++)
                hb[(size_t)n * 64 + fbase + c] = f2bf(acc[c]);
        }
    }

    __syncthreads();
    if (threadIdx.x < 64 && n < N) {
        float s = red[0][0][lane] + red[0][1][lane] + red[0][2][lane] + red[0][3][lane];
        float d = red[1][0][lane] + red[1][1][lane] + red[1][2][lane] + red[1][3][lane];
        asrc[n] = s;
        adst[n] = d;
    }
}

// -------------------- quad-edge aggregation (layers 1-2) --------------------
// Wave split into 4 quarters; quarter q processes edge i+q; lane sub=lane&15
// covers cols [4*sub, 4*sub+4) of the bf16 row via one dwordx2 load (saddr +
// 32-bit voffset: edge byte offset s<<7 staged in LDS). Quarter partials
// combined via shfl_xor(16,32); self term added post-combine.

#define CHUNK 128

template <int FOUT, bool RELU>
__global__ __launch_bounds__(256) void agg_quad_kernel(
    const int* __restrict__ rowptr, const int* __restrict__ csr,
    const float* __restrict__ asrc, const float* __restrict__ adst,
    const unsigned short* __restrict__ hb, const float* __restrict__ bias,
    float* __restrict__ OUT, int N) {
    constexpr int NSUB = FOUT / 4;
    static_assert(FOUT % 4 == 0, "FOUT multiple of 4");
    __shared__ int2 wslds[4][CHUNK];   // {src byte offset (s<<7), w bits}
    const int wv = threadIdx.x >> 6;
    int n = blockIdx.x * 4 + wv;
    if (n >= N) return;
    const int lane = threadIdx.x & 63;
    const int q    = lane >> 4;            // quarter 0..3 -> edge i+q
    const int sub  = lane & 15;            // cols 4sub..4sub+3
    const unsigned int suboff = (unsigned int)sub * 8;   // bytes within row
    const int rs = rowptr[n], re = rowptr[n + 1];
    const float ad_n = adst[n];
    const float wself = __expf(leaky(asrc[n] + ad_n));
    const char* hbb = (const char*)hb;

    float a0 = 0.f, a1 = 0.f, a2 = 0.f, a3 = 0.f;
    float wpart = 0.f;

    for (int base = rs; base < re; base += CHUNK) {
        const int cnt = min(CHUNK, re - base);
        if (lane < cnt) {
            int s = csr[base + lane];
            float w = __expf(leaky(asrc[s] + ad_n));
            wpart += w;
            wslds[wv][lane] = make_int2(s << 7, __float_as_int(w));
        }
        int i = 0;
        for (; i + 4 <= cnt; i += 4) {
            int2 p = wslds[wv][i + q];
            uint2 dv = *(const uint2*)(hbb + ((unsigned int)p.x + suboff));
            float w = __int_as_float(p.y);
            a0 = fmaf(w, bflo(dv.x), a0);
            a1 = fmaf(w, bfhi(dv.x), a1);
            a2 = fmaf(w, bflo(dv.y), a2);
            a3 = fmaf(w, bfhi(dv.y), a3);
        }
        const int rem = cnt - i;
        if (rem) {
            int2 p = wslds[wv][i + ((q < rem) ? q : 0)];
            uint2 dv = *(const uint2*)(hbb + ((unsigned int)p.x + suboff));
            float w = (q < rem) ? __int_as_float(p.y) : 0.f;
            a0 = fmaf(w, bflo(dv.x), a0);
            a1 = fmaf(w, bfhi(dv.x), a1);
            a2 = fmaf(w, bflo(dv.y), a2);
            a3 = fmaf(w, bfhi(dv.y), a3);
        }
    }

    // softmax denominator (each lane staged <=1 edge per chunk)
#pragma unroll
    for (int off = 32; off; off >>= 1) wpart += __shfl_xor(wpart, off, 64);
    const float ssum = wpart + wself;

    // combine quarters -> all lanes hold full sums for their sub
    a0 += __shfl_xor(a0, 16, 64); a0 += __shfl_xor(a0, 32, 64);
    a1 += __shfl_xor(a1, 16, 64); a1 += __shfl_xor(a1, 32, 64);
    a2 += __shfl_xor(a2, 16, 64); a2 += __shfl_xor(a2, 32, 64);
    a3 += __shfl_xor(a3, 16, 64); a3 += __shfl_xor(a3, 32, 64);

    // self term (post-combine: counted once)
    {
        uint2 sv = *(const uint2*)(hbb + (((unsigned int)n << 7) + suboff));
        a0 = fmaf(wself, bflo(sv.x), a0);
        a1 = fmaf(wself, bfhi(sv.x), a1);
        a2 = fmaf(wself, bflo(sv.y), a2);
        a3 = fmaf(wself, bfhi(sv.y), a3);
    }

    if (lane < NSUB) {                     // quarter 0, valid subs only
        const float inv = 1.f / (ssum + 1e-16f);
        float4 bv = *(const float4*)(bias + sub * 4);
        float4 o;
        o.x = a0 * inv + bv.x;
        o.y = a1 * inv + bv.y;
        o.z = a2 * inv + bv.z;
        o.w = a3 * inv + bv.w;
        if (RELU) {
            o.x = fmaxf(o.x, 0.f); o.y = fmaxf(o.y, 0.f);
            o.z = fmaxf(o.z, 0.f); o.w = fmaxf(o.w, 0.f);
        }
        *(float4*)(OUT + (size_t)n * FOUT + sub * 4) = o;
    }
}

// -------------------- quad-edge agg layer 2, fused layer-3 GEMM --------------------

__global__ __launch_bounds__(256) void agg_quad_h3_kernel(
    const int* __restrict__ rowptr, const int* __restrict__ csr,
    const float* __restrict__ asrc, const float* __restrict__ adst,
    const unsigned short* __restrict__ hb, const float* __restrict__ bias,
    const float* __restrict__ W3, float* __restrict__ h3, int N) {
    constexpr int FOUT = 60;
    constexpr int NSUB = FOUT / 4;         // 15
    __shared__ int2 wslds[4][CHUNK];
    const int wv = threadIdx.x >> 6;
    int n = blockIdx.x * 4 + wv;
    if (n >= N) return;
    const int lane = threadIdx.x & 63;
    const int q    = lane >> 4;
    const int sub  = lane & 15;
    const unsigned int suboff = (unsigned int)sub * 8;
    const int rs = rowptr[n], re = rowptr[n + 1];
    const float ad_n = adst[n];
    const float wself = __expf(leaky(asrc[n] + ad_n));
    const char* hbb = (const char*)hb;

    float a0 = 0.f, a1 = 0.f, a2 = 0.f, a3 = 0.f;
    float wpart = 0.f;

    for (int base = rs; base < re; base += CHUNK) {
        const int cnt = min(CHUNK, re - base);
        if (lane < cnt) {
            int s = csr[base + lane];
            float w = __expf(leaky(asrc[s] + ad_n));
            wpart += w;
            wslds[wv][lane] = make_int2(s << 7, __float_as_int(w));
        }
        int i = 0;
        for (; i + 4 <= cnt; i += 4) {
            int2 p = wslds[wv][i + q];
            uint2 dv = *(const uint2*)(hbb + ((unsigned int)p.x + suboff));
            float w = __int_as_float(p.y);
            a0 = fmaf(w, bflo(dv.x), a0);
            a1 = fmaf(w, bfhi(dv.x), a1);
            a2 = fmaf(w, bflo(dv.y), a2);
            a3 = fmaf(w, bfhi(dv.y), a3);
        }
        const int rem = cnt - i;
        if (rem) {
            int2 p = wslds[wv][i + ((q < rem) ? q : 0)];
            uint2 dv = *(const uint2*)(hbb + ((unsigned int)p.x + suboff));
            float w = (q < rem) ? __int_as_float(p.y) : 0.f;
            a0 = fmaf(w, bflo(dv.x), a0);
            a1 = fmaf(w, bfhi(dv.x), a1);
            a2 = fmaf(w, bflo(dv.y), a2);
            a3 = fmaf(w, bfhi(dv.y), a3);
        }
    }

#pragma unroll
    for (int off = 32; off; off >>= 1) wpart += __shfl_xor(wpart, off, 64);
    const float ssum = wpart + wself;

    a0 += __shfl_xor(a0, 16, 64); a0 += __shfl_xor(a0, 32, 64);
    a1 += __shfl_xor(a1, 16, 64); a1 += __shfl_xor(a1, 32, 64);
    a2 += __shfl_xor(a2, 16, 64); a2 += __shfl_xor(a2, 32, 64);
    a3 += __shfl_xor(a3, 16, 64); a3 += __shfl_xor(a3, 32, 64);

    {
        uint2 sv = *(const uint2*)(hbb + (((unsigned int)n << 7) + suboff));
        a0 = fmaf(wself, bflo(sv.x), a0);
        a1 = fmaf(wself, bfhi(sv.x), a1);
        a2 = fmaf(wself, bflo(sv.y), a2);
        a3 = fmaf(wself, bfhi(sv.y), a3);
    }

    // act2 = relu(acc/ssum + bias); fold layer-3 GEMM: t = dot(act2, W3)
    float t = 0.f;
    {
        const int subc = (sub < NSUB) ? sub : 0;    // clamp OOB param loads
        const float inv = 1.f / (ssum + 1e-16f);
        float4 bv = *(const float4*)(bias + subc * 4);
        float4 wv3 = *(const float4*)(W3 + subc * 4);
        float o0 = fmaxf(a0 * inv + bv.x, 0.f);
        float o1 = fmaxf(a1 * inv + bv.y, 0.f);
        float o2 = fmaxf(a2 * inv + bv.z, 0.f);
        float o3 = fmaxf(a3 * inv + bv.w, 0.f);
        if (sub < NSUB)
            t = o0 * wv3.x + o1 * wv3.y + o2 * wv3.z + o3 * wv3.w;
    }
#pragma unroll
    for (int off = 8; off; off >>= 1) t += __shfl_xor(t, off, 64);   // within quarter
    if (lane == 0) h3[n] = t;
}

// -------------------- layer-3 aggregation: alpha derived from h3 --------------------

__global__ __launch_bounds__(256) void agg1_kernel(
    const int* __restrict__ rowptr, const int* __restrict__ csr,
    const float* __restrict__ h3,
    const float* __restrict__ as3p, const float* __restrict__ ad3p,
    const float* __restrict__ bias, float* __restrict__ OUT, int N) {
    int n = blockIdx.x * 4 + (threadIdx.x >> 6);
    if (n >= N) return;
    int lane = threadIdx.x & 63;
    int rs = rowptr[n], re = rowptr[n + 1];
    const float a_s = as3p[0];
    float hn = h3[n];
    float adn = ad3p[0] * hn;
    float wself = __expf(leaky(a_s * hn + adn));

    float ssum = 0.f, accv = 0.f;
    for (int e = rs + lane; e < re; e += 64) {
        float hs = h3[csr[e]];
        float w = __expf(leaky(a_s * hs + adn));
        ssum += w;
        accv = fmaf(w, hs, accv);
    }
#pragma unroll
    for (int off = 32; off; off >>= 1) {
        ssum += __shfl_xor(ssum, off, 64);
        accv += __shfl_xor(accv, off, 64);
    }
    ssum += wself;
    accv = fmaf(wself, hn, accv);
    if (lane == 0) OUT[n] = accv / (ssum + 1e-16f) + bias[0];
}

// -------------------- host launcher --------------------

extern "C" void kernel_launch(void* const* d_in, const int* in_sizes, int n_in,
                              void* d_out, int out_size, void* d_ws, size_t ws_size,
                              hipStream_t stream) {
    const float* x      = (const float*)d_in[0];
    const int*   ei     = (const int*)d_in[1];   // int32 per harness convention
    // d_in[2] = edge_attr: ignored by reference (no edge_dim)
    const float* W1  = (const float*)d_in[3];
    const float* as1 = (const float*)d_in[4];
    const float* ad1 = (const float*)d_in[5];
    const float* b1  = (const float*)d_in[6];
    const float* W2  = (const float*)d_in[7];
    const float* as2 = (const float*)d_in[8];
    const float* ad2 = (const float*)d_in[9];
    const float* b2  = (const float*)d_in[10];
    const float* W3  = (const float*)d_in[11];
    const float* as3 = (const float*)d_in[12];
    const float* ad3 = (const float*)d_in[13];
    const float* b3  = (const float*)d_in[14];

    const int N = in_sizes[0] / 256;   // 50000
    const int E = in_sizes[1] / 2;     // 1600000
    const int K = (N + (1 << BSHIFT) - 1) >> BSHIFT;   // 391 buckets

    char* p = (char*)d_ws;
    auto alloc = [&](size_t bytes) -> void* {
        void* r = (void*)p;
        p += ((bytes + 255) / 256) * 256;
        return r;
    };
    int*   gcursor = (int*)alloc(512 * 4);
    int*   bbase   = (int*)alloc(512 * 4);
    int*   rowptr  = (int*)alloc(((size_t)N + 1) * 4);
    int*   csr     = (int*)alloc((size_t)E * 4);
    unsigned short* hb = (unsigned short*)alloc((size_t)N * 64 * 2);  // bf16 H, 128B rows
    float* actbuf  = (float*)alloc((size_t)N * 48 * 4);               // act1 only
    float* h3      = (float*)alloc((size_t)N * 4);
    float* asrc    = (float*)alloc((size_t)N * 4);
    float* adst    = (float*)alloc((size_t)N * 4);
    // staged bucket regions (8 MB) alias actbuf (9.6 MB, dead until first agg):
    unsigned int* staged = (unsigned int*)actbuf;

    // ---- CSR build (two-level bucketed counting sort) ----
    hipMemsetAsync(gcursor, 0, 512 * 4, stream);
    int cblocks = (E + CTILE - 1) / CTILE;
    coarse_bin_kernel<<<cblocks, 256, 0, stream>>>(ei, staged, gcursor, E, K);
    bucket_scan_kernel<<<1, 512, 0, stream>>>(gcursor, bbase, K);
    fine_sort_kernel<<<K, 256, 0, stream>>>(staged, gcursor, bbase, rowptr, csr, N, E);

    int gblocks = (N + 63) / 64;       // 64 nodes per block (lane = node)
    int ablocks = (N + 3) / 4;

    // ---- layer 1: 256 -> 48, relu (MFMA, W-in-VGPR fp16) ----
    gemm1_mfma_kernel<256><<<gblocks, 256, 0, stream>>>(
        x, W1, as1, ad1, hb, asrc, adst, N);
    agg_quad_kernel<48, true><<<ablocks, 256, 0, stream>>>(rowptr, csr, asrc, adst, hb, b1, actbuf, N);

    // ---- layer 2: 48 -> 60, relu, fused layer-3 GEMM in agg epilogue ----
    gemm_sgpr_kernel<48, 60, 15><<<gblocks, 256, 0, stream>>>(
        actbuf, W2, as2, ad2, hb, asrc, adst, N);
    agg_quad_h3_kernel<<<ablocks, 256, 0, stream>>>(rowptr, csr, asrc, adst, hb, b2, W3, h3, N);

    // ---- layer 3 aggregation: straight to d_out ----
    agg1_kernel<<<ablocks, 256, 0, stream>>>(rowptr, csr, h3, as3, ad3, b3, (float*)d_out, N);
}

// Round 5
// 267.650 us; speedup vs baseline: 1.1390x; 1.0595x over previous
//
#include <hip/hip_runtime.h>
#include <cstdint>
#include <cstddef>

// ---------------------------------------------------------------------------
// GAT 3-layer forward, MI355X.
// Round 17: R16 cut agg VALU work 30% (VALUBusy 56->40) but time was flat ->
// agg is latency-chain-bound, not issue-bound. New agg: per node, ONE latency
// exposure: stage offsets to LDS, issue ALL 8/16 h-row gathers back-to-back
// (wave-uniform branch on cnt, fully unrolled), overlap the asrc-gather+exp+
// w-staging under the h-load flight, then one FMA block. Padded slots use
// self-row offset with w=0 (exact no-op). CHUNK=64 = fully staged (also fixes
// the deg>64 stale-slot hazard R16 inherited). suboff clamped to valid subs:
// layer-1 no longer fetches the 32B/row padding. Everything else = R16.
// ---------------------------------------------------------------------------

__device__ __forceinline__ float leaky(float v) { return v > 0.f ? v : 0.2f * v; }

__device__ __forceinline__ unsigned short f2bf(float x) {
    unsigned int u = __float_as_uint(x);
    u = (u + 0x7FFFu + ((u >> 16) & 1u)) >> 16;   // RNE
    return (unsigned short)u;
}
__device__ __forceinline__ float bf2f(unsigned short b) {
    return __uint_as_float(((unsigned int)b) << 16);
}
__device__ __forceinline__ float bfhi(unsigned int d) {       // high bf16 of dword
    return __uint_as_float(d & 0xFFFF0000u);
}
__device__ __forceinline__ float bflo(unsigned int d) {       // low bf16 of dword
    return __uint_as_float(d << 16);
}

typedef _Float16 half8 __attribute__((ext_vector_type(8)));
typedef float f32x4 __attribute__((ext_vector_type(4)));

#define BSHIFT 7                 // 128 nodes per bucket
#define BCAP   5120              // slots per bucket region (mean 4096, +16 sigma)
#define CTILE  8192              // edges per coarse block

// -------------------- coarse bin: edges -> bucket regions --------------------

__global__ __launch_bounds__(256) void coarse_bin_kernel(
    const int* __restrict__ ei, unsigned int* __restrict__ staged,
    int* __restrict__ gcursor, int E, int K) {
    __shared__ int hist[512];
    __shared__ int rank[512];
    __shared__ int base[512];
    for (int b = threadIdx.x; b < K; b += 256) { hist[b] = 0; rank[b] = 0; }
    __syncthreads();

    int e0 = blockIdx.x * CTILE;
    int e1 = min(E, e0 + CTILE);

    for (int e = e0 + threadIdx.x; e < e1; e += 256) {
        int d = ei[E + e];
        atomicAdd(&hist[d >> BSHIFT], 1);
    }
    __syncthreads();

    for (int b = threadIdx.x; b < K; b += 256) {
        int c = hist[b];
        base[b] = c ? atomicAdd(&gcursor[b], c) : 0;
    }
    __syncthreads();

    for (int e = e0 + threadIdx.x; e < e1; e += 256) {
        int s = ei[e];
        int d = ei[E + e];
        int b = d >> BSHIFT;
        int r = atomicAdd(&rank[b], 1);
        staged[(size_t)b * BCAP + base[b] + r] =
            ((unsigned int)(d & ((1 << BSHIFT) - 1)) << 16) | (unsigned int)s;
    }
}

// -------------------- bucket base scan (1 block) --------------------

__global__ __launch_bounds__(512) void bucket_scan_kernel(
    const int* __restrict__ gcursor, int* __restrict__ bbase, int K) {
    __shared__ int sh[512];
    int t = threadIdx.x;
    int v = (t < K) ? gcursor[t] : 0;
    sh[t] = v;
    __syncthreads();
    for (int off = 1; off < 512; off <<= 1) {
        int a = (t >= off) ? sh[t - off] : 0;
        __syncthreads();
        sh[t] += a;
        __syncthreads();
    }
    if (t < K) bbase[t] = sh[t] - v;   // exclusive
}

// -------------------- fine pass: bucket -> rowptr + sorted csr --------------------

__global__ __launch_bounds__(256) void fine_sort_kernel(
    const unsigned int* __restrict__ staged, const int* __restrict__ gcursor,
    const int* __restrict__ bbase, int* __restrict__ rowptr, int* __restrict__ csr,
    int N, int E) {
    __shared__ int cnt[128];
    __shared__ int off[128];
    __shared__ int lcsr[BCAP];
    const int b = blockIdx.x;
    const int t = threadIdx.x;
    const int c = gcursor[b];
    const int gb = bbase[b];
    const unsigned int* rec = staged + (size_t)b * BCAP;

    if (t < 128) cnt[t] = 0;
    __syncthreads();

    for (int i = t; i < c; i += 256) atomicAdd(&cnt[rec[i] >> 16], 1);
    __syncthreads();

    if (t < 128) off[t] = cnt[t];
    __syncthreads();
    for (int s = 1; s < 128; s <<= 1) {
        int a = (t >= s && t < 128) ? off[t - s] : 0;
        __syncthreads();
        if (t < 128) off[t] += a;
        __syncthreads();
    }

    if (t < 128) {
        int excl = off[t] - cnt[t];
        int n = (b << BSHIFT) + t;
        if (n <= N) rowptr[n] = gb + excl;
        cnt[t] = excl;
    }
    if (b == 0 && t == 0) rowptr[N] = E;
    __syncthreads();

    for (int i = t; i < c; i += 256) {
        unsigned int r = rec[i];
        int p = atomicAdd(&cnt[r >> 16], 1);
        lcsr[p] = (int)(r & 0xFFFFu);
    }
    __syncthreads();

    for (int i = t; i < c; i += 256) csr[gb + i] = lcsr[i];
}

// -------------------- layer-1 GEMM: MFMA, W-in-VGPR fp16 (R15) --------------------

template <int FIN>
__global__ __launch_bounds__(256) void gemm1_mfma_kernel(
    const float* __restrict__ X, const float* __restrict__ W,
    const float* __restrict__ avs, const float* __restrict__ avd,
    unsigned short* __restrict__ hb, float* __restrict__ asrc, float* __restrict__ adst,
    int N) {
    constexpr int FOUT = 48;
    constexpr int KK = FIN / 32;            // 8 k-steps
    static_assert(FIN % 32 == 0, "FIN multiple of 32");

    const int wid  = __builtin_amdgcn_readfirstlane(threadIdx.x >> 6);
    const int lane = threadIdx.x & 63;
    const int col  = lane & 15;             // A-row / D-col index
    const int grp  = lane >> 4;             // k-group
    const int wbase = blockIdx.x * 64 + wid * 16;

    int arow = wbase + col;
    if (arow >= N) arow = N - 1;
    const float* xrow = X + (size_t)arow * FIN + grp * 8;

    // ---- B-fragment preload: 3 n-tiles x KK k-steps, fp16 (96 VGPRs) ----
    half8 Bf[3][KK];
#pragma unroll
    for (int t = 0; t < 3; t++) {
#pragma unroll
        for (int kk = 0; kk < KK; kk++) {
            const float* wp = W + (size_t)(kk * 32 + grp * 8) * FOUT + t * 16 + col;
#pragma unroll
            for (int j = 0; j < 8; j++)
                Bf[t][kk][j] = (_Float16)wp[(size_t)j * FOUT];
        }
    }

    f32x4 acc0 = {0.f, 0.f, 0.f, 0.f};
    f32x4 acc1 = {0.f, 0.f, 0.f, 0.f};
    f32x4 acc2 = {0.f, 0.f, 0.f, 0.f};

#pragma unroll
    for (int kk = 0; kk < KK; kk++) {
        float4 xa = *(const float4*)(xrow + kk * 32);
        float4 xb = *(const float4*)(xrow + kk * 32 + 4);
        float xs[8] = {xa.x, xa.y, xa.z, xa.w, xb.x, xb.y, xb.z, xb.w};
        half8 ah, al;
#pragma unroll
        for (int j = 0; j < 8; j++) {
            _Float16 h = (_Float16)xs[j];
            ah[j] = h;
            al[j] = (_Float16)(xs[j] - (float)h);   // exact residual -> fp16
        }
        acc0 = __builtin_amdgcn_mfma_f32_16x16x32_f16(ah, Bf[0][kk], acc0, 0, 0, 0);
        acc1 = __builtin_amdgcn_mfma_f32_16x16x32_f16(ah, Bf[1][kk], acc1, 0, 0, 0);
        acc2 = __builtin_amdgcn_mfma_f32_16x16x32_f16(ah, Bf[2][kk], acc2, 0, 0, 0);
        acc0 = __builtin_amdgcn_mfma_f32_16x16x32_f16(al, Bf[0][kk], acc0, 0, 0, 0);
        acc1 = __builtin_amdgcn_mfma_f32_16x16x32_f16(al, Bf[1][kk], acc1, 0, 0, 0);
        acc2 = __builtin_amdgcn_mfma_f32_16x16x32_f16(al, Bf[2][kk], acc2, 0, 0, 0);
    }

    // ---- alpha partials: lane holds fout col of nodes wbase+grp*4+r ----
    float avs0 = avs[col], avs1 = avs[16 + col], avs2 = avs[32 + col];
    float avd0 = avd[col], avd1 = avd[16 + col], avd2 = avd[32 + col];

#pragma unroll
    for (int r = 0; r < 4; r++) {
        float ps = acc0[r] * avs0 + acc1[r] * avs1 + acc2[r] * avs2;
        float pd = acc0[r] * avd0 + acc1[r] * avd1 + acc2[r] * avd2;
#pragma unroll
        for (int off = 8; off; off >>= 1) {
            ps += __shfl_xor(ps, off, 64);
            pd += __shfl_xor(pd, off, 64);
        }
        int nd = wbase + grp * 4 + r;
        if (col == r && nd < N) { asrc[nd] = ps; adst[nd] = pd; }
    }

    // ---- h store (bf16, 64-entry padded rows) ----
#pragma unroll
    for (int r = 0; r < 4; r++) {
        int nd = wbase + grp * 4 + r;
        if (nd < N) {
            unsigned short* hp = hb + (size_t)nd * 64 + col;
            hp[0]  = f2bf(acc0[r]);
            hp[16] = f2bf(acc1[r]);
            hp[32] = f2bf(acc2[r]);
        }
    }
}

// -------------------- layer-2 GEMM (R12 structure: fout split, s_load W) ----

template <int FIN, int FOUT, int FT>
__global__ __launch_bounds__(256) void gemm_sgpr_kernel(
    const float* __restrict__ X, const float* __restrict__ W,
    const float* __restrict__ avs, const float* __restrict__ avd,
    unsigned short* __restrict__ hb, float* __restrict__ asrc, float* __restrict__ adst,
    int N) {
    static_assert(4 * FT == FOUT, "FT must be FOUT/4");
    __shared__ float red[2][4][64];

    const int wid  = __builtin_amdgcn_readfirstlane(threadIdx.x >> 6); // wave id 0..3
    const int lane = threadIdx.x & 63;
    const int n    = blockIdx.x * 64 + lane;
    const int nc   = (n < N) ? n : N - 1;     // clamp loads; stores guarded
    const int fbase = wid * FT;               // uniform

    const float* xrow = X + (size_t)nc * FIN;

    float acc[FT];
#pragma unroll
    for (int c = 0; c < FT; c++) acc[c] = 0.f;

#pragma unroll
    for (int k = 0; k < FIN; k += 4) {
        float4 xv = *(const float4*)(xrow + k);
        const float* w0 = W + (size_t)k * FOUT + fbase;   // uniform base
#pragma unroll
        for (int c = 0; c < FT; c++) {
            acc[c] = fmaf(xv.x, w0[c],            acc[c]);
            acc[c] = fmaf(xv.y, w0[FOUT + c],     acc[c]);
            acc[c] = fmaf(xv.z, w0[2 * FOUT + c], acc[c]);
            acc[c] = fmaf(xv.w, w0[3 * FOUT + c], acc[c]);
        }
    }

    // alpha partials over this wave's fout subset (avs/avd loads are uniform)
    float ps = 0.f, pd = 0.f;
#pragma unroll
    for (int c = 0; c < FT; c++) {
        ps = fmaf(acc[c], avs[fbase + c], ps);
        pd = fmaf(acc[c], avd[fbase + c], pd);
    }
    red[0][wid][lane] = ps;
    red[1][wid][lane] = pd;

    // h store (bf16, padded 64-entry rows)
    if (n < N) {
        if constexpr ((FT & 1) == 0) {
            unsigned int* dst = (unsigned int*)(hb + (size_t)n * 64 + fbase);
#pragma unroll
            for (int c = 0; c < FT; c += 2) {
                unsigned int pk = (unsigned int)f2bf(acc[c]) |
                                  ((unsigned int)f2bf(acc[c + 1]) << 16);
                dst[c >> 1] = pk;
            }
        } else {
#pragma unroll
            for (int c = 0; c < FT; c++)
                hb[(size_t)n * 64 + fbase + c] = f2bf(acc[c]);
        }
    }

    __syncthreads();
    if (threadIdx.x < 64 && n < N) {
        float s = red[0][0][lane] + red[0][1][lane] + red[0][2][lane] + red[0][3][lane];
        float d = red[1][0][lane] + red[1][1][lane] + red[1][2][lane] + red[1][3][lane];
        asrc[n] = s;
        adst[n] = d;
    }
}

// -------------------- pipelined quad-edge aggregation --------------------
// CHUNK=64: every staged slot is written each chunk (lane>=cnt -> self row,
// w=0: exact no-op). Consumption: wave-uniform branch on cnt issues ALL 8 or
// 16 h-row gathers back-to-back (one latency exposure); asrc gather + exp +
// w-staging overlap under the h-load flight (counted vmcnt, no drain).

#define GATHER_STEP(NG)                                                        \
    {                                                                          \
        int   off_[NG];                                                        \
        uint2 hd_[NG];                                                         \
        float ww_[NG];                                                         \
        _Pragma("unroll")                                                      \
        for (int u = 0; u < NG; u++) off_[u] = offlds[wv][4 * u + q];          \
        _Pragma("unroll")                                                      \
        for (int u = 0; u < NG; u++)                                           \
            hd_[u] = *(const uint2*)(hbb + ((unsigned int)off_[u] + suboff));  \
        float we = (lane < cnt) ? __expf(leaky(as + ad_n)) : 0.f;              \
        wpart += we;                                                           \
        wlds[wv][lane] = we;                                                   \
        _Pragma("unroll")                                                      \
        for (int u = 0; u < NG; u++) ww_[u] = wlds[wv][4 * u + q];             \
        _Pragma("unroll")                                                      \
        for (int u = 0; u < NG; u++) {                                         \
            a0 = fmaf(ww_[u], bflo(hd_[u].x), a0);                             \
            a1 = fmaf(ww_[u], bfhi(hd_[u].x), a1);                             \
            a2 = fmaf(ww_[u], bflo(hd_[u].y), a2);                             \
            a3 = fmaf(ww_[u], bfhi(hd_[u].y), a3);                             \
        }                                                                      \
    }

template <int FOUT, bool RELU>
__global__ __launch_bounds__(256) void agg_pipe_kernel(
    const int* __restrict__ rowptr, const int* __restrict__ csr,
    const float* __restrict__ asrc, const float* __restrict__ adst,
    const unsigned short* __restrict__ hb, const float* __restrict__ bias,
    float* __restrict__ OUT, int N) {
    constexpr int NSUB = FOUT / 4;
    static_assert(FOUT % 4 == 0, "FOUT multiple of 4");
    __shared__ int   offlds[4][64];
    __shared__ float wlds[4][64];
    const int wv = threadIdx.x >> 6;
    int n = blockIdx.x * 4 + wv;
    if (n >= N) return;
    const int lane = threadIdx.x & 63;
    const int q    = lane >> 4;            // quarter 0..3 -> slot 4u+q
    const int sub  = lane & 15;
    const int subc = (sub < NSUB) ? sub : NSUB - 1;   // clamp: no padding fetch
    const unsigned int suboff = (unsigned int)subc * 8;
    const int rs = rowptr[n], re = rowptr[n + 1];
    const float ad_n = adst[n];
    const float wself = __expf(leaky(asrc[n] + ad_n));
    const char* hbb = (const char*)hb;

    float a0 = 0.f, a1 = 0.f, a2 = 0.f, a3 = 0.f;
    float wpart = 0.f;

    for (int base = rs; base < re; base += 64) {
        const int cnt = min(64, re - base);
        int ce = base + lane;
        if (ce >= re) ce = re - 1;                  // clamp load addr
        int sv = csr[ce];
        int sidx = (lane < cnt) ? sv : n;           // padded -> self row (w=0)
        offlds[wv][lane] = sidx << 7;
        float as = asrc[sidx];
        if (cnt <= 32) { GATHER_STEP(8) } else { GATHER_STEP(16) }
    }

    // softmax denominator
#pragma unroll
    for (int off = 32; off; off >>= 1) wpart += __shfl_xor(wpart, off, 64);
    const float ssum = wpart + wself;

    // combine quarters -> all lanes hold full sums for their sub
    a0 += __shfl_xor(a0, 16, 64); a0 += __shfl_xor(a0, 32, 64);
    a1 += __shfl_xor(a1, 16, 64); a1 += __shfl_xor(a1, 32, 64);
    a2 += __shfl_xor(a2, 16, 64); a2 += __shfl_xor(a2, 32, 64);
    a3 += __shfl_xor(a3, 16, 64); a3 += __shfl_xor(a3, 32, 64);

    // self term (post-combine: counted once)
    {
        uint2 sv = *(const uint2*)(hbb + (((unsigned int)n << 7) + suboff));
        a0 = fmaf(wself, bflo(sv.x), a0);
        a1 = fmaf(wself, bfhi(sv.x), a1);
        a2 = fmaf(wself, bflo(sv.y), a2);
        a3 = fmaf(wself, bfhi(sv.y), a3);
    }

    if (lane < NSUB) {                     // quarter 0, valid subs only
        const float inv = 1.f / (ssum + 1e-16f);
        float4 bv = *(const float4*)(bias + sub * 4);
        float4 o;
        o.x = a0 * inv + bv.x;
        o.y = a1 * inv + bv.y;
        o.z = a2 * inv + bv.z;
        o.w = a3 * inv + bv.w;
        if (RELU) {
            o.x = fmaxf(o.x, 0.f); o.y = fmaxf(o.y, 0.f);
            o.z = fmaxf(o.z, 0.f); o.w = fmaxf(o.w, 0.f);
        }
        *(float4*)(OUT + (size_t)n * FOUT + sub * 4) = o;
    }
}

// -------------------- pipelined agg layer 2, fused layer-3 GEMM --------------------

__global__ __launch_bounds__(256) void agg_pipe_h3_kernel(
    const int* __restrict__ rowptr, const int* __restrict__ csr,
    const float* __restrict__ asrc, const float* __restrict__ adst,
    const unsigned short* __restrict__ hb, const float* __restrict__ bias,
    const float* __restrict__ W3, float* __restrict__ h3, int N) {
    constexpr int FOUT = 60;
    constexpr int NSUB = FOUT / 4;         // 15
    __shared__ int   offlds[4][64];
    __shared__ float wlds[4][64];
    const int wv = threadIdx.x >> 6;
    int n = blockIdx.x * 4 + wv;
    if (n >= N) return;
    const int lane = threadIdx.x & 63;
    const int q    = lane >> 4;
    const int sub  = lane & 15;
    const int subc = (sub < NSUB) ? sub : NSUB - 1;
    const unsigned int suboff = (unsigned int)subc * 8;
    const int rs = rowptr[n], re = rowptr[n + 1];
    const float ad_n = adst[n];
    const float wself = __expf(leaky(asrc[n] + ad_n));
    const char* hbb = (const char*)hb;

    float a0 = 0.f, a1 = 0.f, a2 = 0.f, a3 = 0.f;
    float wpart = 0.f;

    for (int base = rs; base < re; base += 64) {
        const int cnt = min(64, re - base);
        int ce = base + lane;
        if (ce >= re) ce = re - 1;
        int sv = csr[ce];
        int sidx = (lane < cnt) ? sv : n;
        offlds[wv][lane] = sidx << 7;
        float as = asrc[sidx];
        if (cnt <= 32) { GATHER_STEP(8) } else { GATHER_STEP(16) }
    }

#pragma unroll
    for (int off = 32; off; off >>= 1) wpart += __shfl_xor(wpart, off, 64);
    const float ssum = wpart + wself;

    a0 += __shfl_xor(a0, 16, 64); a0 += __shfl_xor(a0, 32, 64);
    a1 += __shfl_xor(a1, 16, 64); a1 += __shfl_xor(a1, 32, 64);
    a2 += __shfl_xor(a2, 16, 64); a2 += __shfl_xor(a2, 32, 64);
    a3 += __shfl_xor(a3, 16, 64); a3 += __shfl_xor(a3, 32, 64);

    {
        uint2 sv = *(const uint2*)(hbb + (((unsigned int)n << 7) + suboff));
        a0 = fmaf(wself, bflo(sv.x), a0);
        a1 = fmaf(wself, bfhi(sv.x), a1);
        a2 = fmaf(wself, bflo(sv.y), a2);
        a3 = fmaf(wself, bfhi(sv.y), a3);
    }

    // act2 = relu(acc/ssum + bias); fold layer-3 GEMM: t = dot(act2, W3)
    float t = 0.f;
    {
        const float inv = 1.f / (ssum + 1e-16f);
        float4 bv = *(const float4*)(bias + subc * 4);
        float4 wv3 = *(const float4*)(W3 + subc * 4);
        float o0 = fmaxf(a0 * inv + bv.x, 0.f);
        float o1 = fmaxf(a1 * inv + bv.y, 0.f);
        float o2 = fmaxf(a2 * inv + bv.z, 0.f);
        float o3 = fmaxf(a3 * inv + bv.w, 0.f);
        if (sub < NSUB)
            t = o0 * wv3.x + o1 * wv3.y + o2 * wv3.z + o3 * wv3.w;
    }
#pragma unroll
    for (int off = 8; off; off >>= 1) t += __shfl_xor(t, off, 64);   // within quarter
    if (lane == 0) h3[n] = t;
}

// -------------------- layer-3 aggregation: alpha derived from h3 --------------------

__global__ __launch_bounds__(256) void agg1_kernel(
    const int* __restrict__ rowptr, const int* __restrict__ csr,
    const float* __restrict__ h3,
    const float* __restrict__ as3p, const float* __restrict__ ad3p,
    const float* __restrict__ bias, float* __restrict__ OUT, int N) {
    int n = blockIdx.x * 4 + (threadIdx.x >> 6);
    if (n >= N) return;
    int lane = threadIdx.x & 63;
    int rs = rowptr[n], re = rowptr[n + 1];
    const float a_s = as3p[0];
    float hn = h3[n];
    float adn = ad3p[0] * hn;
    float wself = __expf(leaky(a_s * hn + adn));

    float ssum = 0.f, accv = 0.f;
    for (int e = rs + lane; e < re; e += 64) {
        float hs = h3[csr[e]];
        float w = __expf(leaky(a_s * hs + adn));
        ssum += w;
        accv = fmaf(w, hs, accv);
    }
#pragma unroll
    for (int off = 32; off; off >>= 1) {
        ssum += __shfl_xor(ssum, off, 64);
        accv += __shfl_xor(accv, off, 64);
    }
    ssum += wself;
    accv = fmaf(wself, hn, accv);
    if (lane == 0) OUT[n] = accv / (ssum + 1e-16f) + bias[0];
}

// -------------------- host launcher --------------------

extern "C" void kernel_launch(void* const* d_in, const int* in_sizes, int n_in,
                              void* d_out, int out_size, void* d_ws, size_t ws_size,
                              hipStream_t stream) {
    const float* x      = (const float*)d_in[0];
    const int*   ei     = (const int*)d_in[1];   // int32 per harness convention
    // d_in[2] = edge_attr: ignored by reference (no edge_dim)
    const float* W1  = (const float*)d_in[3];
    const float* as1 = (const float*)d_in[4];
    const float* ad1 = (const float*)d_in[5];
    const float* b1  = (const float*)d_in[6];
    const float* W2  = (const float*)d_in[7];
    const float* as2 = (const float*)d_in[8];
    const float* ad2 = (const float*)d_in[9];
    const float* b2  = (const float*)d_in[10];
    const float* W3  = (const float*)d_in[11];
    const float* as3 = (const float*)d_in[12];
    const float* ad3 = (const float*)d_in[13];
    const float* b3  = (const float*)d_in[14];

    const int N = in_sizes[0] / 256;   // 50000
    const int E = in_sizes[1] / 2;     // 1600000
    const int K = (N + (1 << BSHIFT) - 1) >> BSHIFT;   // 391 buckets

    char* p = (char*)d_ws;
    auto alloc = [&](size_t bytes) -> void* {
        void* r = (void*)p;
        p += ((bytes + 255) / 256) * 256;
        return r;
    };
    int*   gcursor = (int*)alloc(512 * 4);
    int*   bbase   = (int*)alloc(512 * 4);
    int*   rowptr  = (int*)alloc(((size_t)N + 1) * 4);
    int*   csr     = (int*)alloc((size_t)E * 4);
    unsigned short* hb = (unsigned short*)alloc((size_t)N * 64 * 2);  // bf16 H, 128B rows
    float* actbuf  = (float*)alloc((size_t)N * 48 * 4);               // act1 only
    float* h3      = (float*)alloc((size_t)N * 4);
    float* asrc    = (float*)alloc((size_t)N * 4);
    float* adst    = (float*)alloc((size_t)N * 4);
    // staged bucket regions (8 MB) alias actbuf (9.6 MB, dead until first agg):
    unsigned int* staged = (unsigned int*)actbuf;

    // ---- CSR build (two-level bucketed counting sort) ----
    hipMemsetAsync(gcursor, 0, 512 * 4, stream);
    int cblocks = (E + CTILE - 1) / CTILE;
    coarse_bin_kernel<<<cblocks, 256, 0, stream>>>(ei, staged, gcursor, E, K);
    bucket_scan_kernel<<<1, 512, 0, stream>>>(gcursor, bbase, K);
    fine_sort_kernel<<<K, 256, 0, stream>>>(staged, gcursor, bbase, rowptr, csr, N, E);

    int gblocks = (N + 63) / 64;       // 64 nodes per block (lane = node)
    int ablocks = (N + 3) / 4;

    // ---- layer 1: 256 -> 48, relu (MFMA, W-in-VGPR fp16) ----
    gemm1_mfma_kernel<256><<<gblocks, 256, 0, stream>>>(
        x, W1, as1, ad1, hb, asrc, adst, N);
    agg_pipe_kernel<48, true><<<ablocks, 256, 0, stream>>>(rowptr, csr, asrc, adst, hb, b1, actbuf, N);

    // ---- layer 2: 48 -> 60, relu, fused layer-3 GEMM in agg epilogue ----
    gemm_sgpr_kernel<48, 60, 15><<<gblocks, 256, 0, stream>>>(
        actbuf, W2, as2, ad2, hb, asrc, adst, N);
    agg_pipe_h3_kernel<<<ablocks, 256, 0, stream>>>(rowptr, csr, asrc, adst, hb, b2, W3, h3, N);

    // ---- layer 3 aggregation: straight to d_out ----
    agg1_kernel<<<ablocks, 256, 0, stream>>>(rowptr, csr, h3, as3, ad3, b3, (float*)d_out, N);
}

// Round 8
// 255.816 us; speedup vs baseline: 1.1917x; 1.0463x over previous
//
#include <hip/hip_runtime.h>
#include <cstdint>
#include <cstddef>

// ---------------------------------------------------------------------------
// GAT 3-layer forward, MI355X.
// Round 19 (resubmit; R7 bench was an infra failure, kernel never evaluated).
// R18 failed the post-timing check (replay outputs self-consistent but
// diverged from first launch) -> one of its 3 fusions carries launch-state
// dependence. Bisect: REVERT fusion (C) (agg+gemm2; back to R17's proven
// agg_pipe<48> -> gemm_sgpr -> agg_pipe_h3 chain, identical code + buffers);
// KEEP (A) coarse+gemm1 heterogeneous-grid fusion (disjoint writes: staged/
// gcursor vs hb/asrc/adst) and (B) bucket_scan folded into fine_sort (exact
// integer reduction). 9 dispatches -> 7.
// ---------------------------------------------------------------------------

__device__ __forceinline__ float leaky(float v) { return v > 0.f ? v : 0.2f * v; }

__device__ __forceinline__ unsigned short f2bf(float x) {
    unsigned int u = __float_as_uint(x);
    u = (u + 0x7FFFu + ((u >> 16) & 1u)) >> 16;   // RNE
    return (unsigned short)u;
}
__device__ __forceinline__ float bf2f(unsigned short b) {
    return __uint_as_float(((unsigned int)b) << 16);
}
__device__ __forceinline__ float bfhi(unsigned int d) {
    return __uint_as_float(d & 0xFFFF0000u);
}
__device__ __forceinline__ float bflo(unsigned int d) {
    return __uint_as_float(d << 16);
}

typedef _Float16 half8 __attribute__((ext_vector_type(8)));
typedef float f32x4 __attribute__((ext_vector_type(4)));

#define BSHIFT 7                 // 128 nodes per bucket
#define BCAP   5120              // slots per bucket region (mean 4096, +16 sigma)
#define CTILE  8192              // edges per coarse block

// -------------------- fused: coarse bin (blocks < cblocks) + gemm1 MFMA ------

template <int FIN>
__global__ __launch_bounds__(256) void coarse_gemm1_kernel(
    const int* __restrict__ ei, unsigned int* __restrict__ staged,
    int* __restrict__ gcursor, int E, int K, int cblocks,
    const float* __restrict__ X, const float* __restrict__ W,
    const float* __restrict__ avs, const float* __restrict__ avd,
    unsigned short* __restrict__ hb, float* __restrict__ asrc,
    float* __restrict__ adst, int N) {

    if ((int)blockIdx.x < cblocks) {
        // ---------------- coarse bin (R17 coarse_bin_kernel, verbatim) ------
        __shared__ int hist[512];
        __shared__ int rank[512];
        __shared__ int base[512];
        for (int b = threadIdx.x; b < K; b += 256) { hist[b] = 0; rank[b] = 0; }
        __syncthreads();

        int e0 = blockIdx.x * CTILE;
        int e1 = min(E, e0 + CTILE);

        for (int e = e0 + threadIdx.x; e < e1; e += 256) {
            int d = ei[E + e];
            atomicAdd(&hist[d >> BSHIFT], 1);
        }
        __syncthreads();

        for (int b = threadIdx.x; b < K; b += 256) {
            int c = hist[b];
            base[b] = c ? atomicAdd(&gcursor[b], c) : 0;
        }
        __syncthreads();

        for (int e = e0 + threadIdx.x; e < e1; e += 256) {
            int s = ei[e];
            int d = ei[E + e];
            int b = d >> BSHIFT;
            int r = atomicAdd(&rank[b], 1);
            staged[(size_t)b * BCAP + base[b] + r] =
                ((unsigned int)(d & ((1 << BSHIFT) - 1)) << 16) | (unsigned int)s;
        }
        return;
    }

    // ---------------- gemm1: MFMA, W-in-VGPR fp16 (R15, verbatim) ----------
    constexpr int FOUT = 48;
    constexpr int KK = FIN / 32;
    static_assert(FIN % 32 == 0, "FIN multiple of 32");

    const int bid  = (int)blockIdx.x - cblocks;
    const int wid  = __builtin_amdgcn_readfirstlane(threadIdx.x >> 6);
    const int lane = threadIdx.x & 63;
    const int col  = lane & 15;
    const int grp  = lane >> 4;
    const int wbase = bid * 64 + wid * 16;

    int arow = wbase + col;
    if (arow >= N) arow = N - 1;
    const float* xrow = X + (size_t)arow * FIN + grp * 8;

    half8 Bf[3][KK];
#pragma unroll
    for (int t = 0; t < 3; t++) {
#pragma unroll
        for (int kk = 0; kk < KK; kk++) {
            const float* wp = W + (size_t)(kk * 32 + grp * 8) * FOUT + t * 16 + col;
#pragma unroll
            for (int j = 0; j < 8; j++)
                Bf[t][kk][j] = (_Float16)wp[(size_t)j * FOUT];
        }
    }

    f32x4 acc0 = {0.f, 0.f, 0.f, 0.f};
    f32x4 acc1 = {0.f, 0.f, 0.f, 0.f};
    f32x4 acc2 = {0.f, 0.f, 0.f, 0.f};

#pragma unroll
    for (int kk = 0; kk < KK; kk++) {
        float4 xa = *(const float4*)(xrow + kk * 32);
        float4 xb = *(const float4*)(xrow + kk * 32 + 4);
        float xs[8] = {xa.x, xa.y, xa.z, xa.w, xb.x, xb.y, xb.z, xb.w};
        half8 ah, al;
#pragma unroll
        for (int j = 0; j < 8; j++) {
            _Float16 h = (_Float16)xs[j];
            ah[j] = h;
            al[j] = (_Float16)(xs[j] - (float)h);
        }
        acc0 = __builtin_amdgcn_mfma_f32_16x16x32_f16(ah, Bf[0][kk], acc0, 0, 0, 0);
        acc1 = __builtin_amdgcn_mfma_f32_16x16x32_f16(ah, Bf[1][kk], acc1, 0, 0, 0);
        acc2 = __builtin_amdgcn_mfma_f32_16x16x32_f16(ah, Bf[2][kk], acc2, 0, 0, 0);
        acc0 = __builtin_amdgcn_mfma_f32_16x16x32_f16(al, Bf[0][kk], acc0, 0, 0, 0);
        acc1 = __builtin_amdgcn_mfma_f32_16x16x32_f16(al, Bf[1][kk], acc1, 0, 0, 0);
        acc2 = __builtin_amdgcn_mfma_f32_16x16x32_f16(al, Bf[2][kk], acc2, 0, 0, 0);
    }

    float avs0 = avs[col], avs1 = avs[16 + col], avs2 = avs[32 + col];
    float avd0 = avd[col], avd1 = avd[16 + col], avd2 = avd[32 + col];

#pragma unroll
    for (int r = 0; r < 4; r++) {
        float ps = acc0[r] * avs0 + acc1[r] * avs1 + acc2[r] * avs2;
        float pd = acc0[r] * avd0 + acc1[r] * avd1 + acc2[r] * avd2;
#pragma unroll
        for (int off = 8; off; off >>= 1) {
            ps += __shfl_xor(ps, off, 64);
            pd += __shfl_xor(pd, off, 64);
        }
        int nd = wbase + grp * 4 + r;
        if (col == r && nd < N) { asrc[nd] = ps; adst[nd] = pd; }
    }

#pragma unroll
    for (int r = 0; r < 4; r++) {
        int nd = wbase + grp * 4 + r;
        if (nd < N) {
            unsigned short* hp = hb + (size_t)nd * 64 + col;
            hp[0]  = f2bf(acc0[r]);
            hp[16] = f2bf(acc1[r]);
            hp[32] = f2bf(acc2[r]);
        }
    }
}

// -------------------- fine pass (with integrated bucket-base reduction) -----

__global__ __launch_bounds__(256) void fine_sort_kernel(
    const unsigned int* __restrict__ staged, const int* __restrict__ gcursor,
    int* __restrict__ rowptr, int* __restrict__ csr, int N, int E) {
    __shared__ int cnt[128];
    __shared__ int off[128];
    __shared__ int gbred[4];
    __shared__ int lcsr[BCAP];
    const int b = blockIdx.x;
    const int t = threadIdx.x;
    const int c = gcursor[b];
    const unsigned int* rec = staged + (size_t)b * BCAP;

    // gb = sum_{i<b} gcursor[i]   (replaces the bucket_scan dispatch)
    int pacc = 0;
    for (int i = t; i < b; i += 256) pacc += gcursor[i];
#pragma unroll
    for (int o2 = 32; o2; o2 >>= 1) pacc += __shfl_xor(pacc, o2, 64);
    if ((t & 63) == 0) gbred[t >> 6] = pacc;

    if (t < 128) cnt[t] = 0;
    __syncthreads();
    const int gb = gbred[0] + gbred[1] + gbred[2] + gbred[3];

    for (int i = t; i < c; i += 256) atomicAdd(&cnt[rec[i] >> 16], 1);
    __syncthreads();

    if (t < 128) off[t] = cnt[t];
    __syncthreads();
    for (int s = 1; s < 128; s <<= 1) {
        int a = (t >= s && t < 128) ? off[t - s] : 0;
        __syncthreads();
        if (t < 128) off[t] += a;
        __syncthreads();
    }

    if (t < 128) {
        int excl = off[t] - cnt[t];
        int n = (b << BSHIFT) + t;
        if (n <= N) rowptr[n] = gb + excl;
        cnt[t] = excl;
    }
    if (b == 0 && t == 0) rowptr[N] = E;
    __syncthreads();

    for (int i = t; i < c; i += 256) {
        unsigned int r = rec[i];
        int p = atomicAdd(&cnt[r >> 16], 1);
        lcsr[p] = (int)(r & 0xFFFFu);
    }
    __syncthreads();

    for (int i = t; i < c; i += 256) csr[gb + i] = lcsr[i];
}

// -------------------- layer-2 GEMM (R12 structure: fout split, s_load W) ----

template <int FIN, int FOUT, int FT>
__global__ __launch_bounds__(256) void gemm_sgpr_kernel(
    const float* __restrict__ X, const float* __restrict__ W,
    const float* __restrict__ avs, const float* __restrict__ avd,
    unsigned short* __restrict__ hb, float* __restrict__ asrc, float* __restrict__ adst,
    int N) {
    static_assert(4 * FT == FOUT, "FT must be FOUT/4");
    __shared__ float red[2][4][64];

    const int wid  = __builtin_amdgcn_readfirstlane(threadIdx.x >> 6); // wave id 0..3
    const int lane = threadIdx.x & 63;
    const int n    = blockIdx.x * 64 + lane;
    const int nc   = (n < N) ? n : N - 1;     // clamp loads; stores guarded
    const int fbase = wid * FT;               // uniform

    const float* xrow = X + (size_t)nc * FIN;

    float acc[FT];
#pragma unroll
    for (int c = 0; c < FT; c++) acc[c] = 0.f;

#pragma unroll
    for (int k = 0; k < FIN; k += 4) {
        float4 xv = *(const float4*)(xrow + k);
        const float* w0 = W + (size_t)k * FOUT + fbase;   // uniform base
#pragma unroll
        for (int c = 0; c < FT; c++) {
            acc[c] = fmaf(xv.x, w0[c],            acc[c]);
            acc[c] = fmaf(xv.y, w0[FOUT + c],     acc[c]);
            acc[c] = fmaf(xv.z, w0[2 * FOUT + c], acc[c]);
            acc[c] = fmaf(xv.w, w0[3 * FOUT + c], acc[c]);
        }
    }

    // alpha partials over this wave's fout subset (avs/avd loads are uniform)
    float ps = 0.f, pd = 0.f;
#pragma unroll
    for (int c = 0; c < FT; c++) {
        ps = fmaf(acc[c], avs[fbase + c], ps);
        pd = fmaf(acc[c], avd[fbase + c], pd);
    }
    red[0][wid][lane] = ps;
    red[1][wid][lane] = pd;

    // h store (bf16, padded 64-entry rows)
    if (n < N) {
        if constexpr ((FT & 1) == 0) {
            unsigned int* dst = (unsigned int*)(hb + (size_t)n * 64 + fbase);
#pragma unroll
            for (int c = 0; c < FT; c += 2) {
                unsigned int pk = (unsigned int)f2bf(acc[c]) |
                                  ((unsigned int)f2bf(acc[c + 1]) << 16);
                dst[c >> 1] = pk;
            }
        } else {
#pragma unroll
            for (int c = 0; c < FT; c++)
                hb[(size_t)n * 64 + fbase + c] = f2bf(acc[c]);
        }
    }

    __syncthreads();
    if (threadIdx.x < 64 && n < N) {
        float s = red[0][0][lane] + red[0][1][lane] + red[0][2][lane] + red[0][3][lane];
        float d = red[1][0][lane] + red[1][1][lane] + red[1][2][lane] + red[1][3][lane];
        asrc[n] = s;
        adst[n] = d;
    }
}

// -------------------- pipelined gather step (R17) --------------------

#define GATHER_STEP(NG)                                                        \
    {                                                                          \
        int   off_[NG];                                                        \
        uint2 hd_[NG];                                                         \
        float ww_[NG];                                                         \
        _Pragma("unroll")                                                      \
        for (int u = 0; u < NG; u++) off_[u] = offlds[wv][4 * u + q];          \
        _Pragma("unroll")                                                      \
        for (int u = 0; u < NG; u++)                                           \
            hd_[u] = *(const uint2*)(hbb + ((unsigned int)off_[u] + suboff));  \
        float we = (lane < cnt) ? __expf(leaky(as + ad_n)) : 0.f;              \
        wpart += we;                                                           \
        wlds[wv][lane] = we;                                                   \
        _Pragma("unroll")                                                      \
        for (int u = 0; u < NG; u++) ww_[u] = wlds[wv][4 * u + q];             \
        _Pragma("unroll")                                                      \
        for (int u = 0; u < NG; u++) {                                         \
            a0 = fmaf(ww_[u], bflo(hd_[u].x), a0);                             \
            a1 = fmaf(ww_[u], bfhi(hd_[u].x), a1);                             \
            a2 = fmaf(ww_[u], bflo(hd_[u].y), a2);                             \
            a3 = fmaf(ww_[u], bfhi(hd_[u].y), a3);                             \
        }                                                                      \
    }

// -------------------- pipelined quad-edge aggregation (R17) --------------------

template <int FOUT, bool RELU>
__global__ __launch_bounds__(256) void agg_pipe_kernel(
    const int* __restrict__ rowptr, const int* __restrict__ csr,
    const float* __restrict__ asrc, const float* __restrict__ adst,
    const unsigned short* __restrict__ hb, const float* __restrict__ bias,
    float* __restrict__ OUT, int N) {
    constexpr int NSUB = FOUT / 4;
    static_assert(FOUT % 4 == 0, "FOUT multiple of 4");
    __shared__ int   offlds[4][64];
    __shared__ float wlds[4][64];
    const int wv = threadIdx.x >> 6;
    int n = blockIdx.x * 4 + wv;
    if (n >= N) return;
    const int lane = threadIdx.x & 63;
    const int q    = lane >> 4;            // quarter 0..3 -> slot 4u+q
    const int sub  = lane & 15;
    const int subc = (sub < NSUB) ? sub : NSUB - 1;   // clamp: no padding fetch
    const unsigned int suboff = (unsigned int)subc * 8;
    const int rs = rowptr[n], re = rowptr[n + 1];
    const float ad_n = adst[n];
    const float wself = __expf(leaky(asrc[n] + ad_n));
    const char* hbb = (const char*)hb;

    float a0 = 0.f, a1 = 0.f, a2 = 0.f, a3 = 0.f;
    float wpart = 0.f;

    for (int base = rs; base < re; base += 64) {
        const int cnt = min(64, re - base);
        int ce = base + lane;
        if (ce >= re) ce = re - 1;                  // clamp load addr
        int sv = csr[ce];
        int sidx = (lane < cnt) ? sv : n;           // padded -> self row (w=0)
        offlds[wv][lane] = sidx << 7;
        float as = asrc[sidx];
        if (cnt <= 32) { GATHER_STEP(8) } else { GATHER_STEP(16) }
    }

    // softmax denominator
#pragma unroll
    for (int off = 32; off; off >>= 1) wpart += __shfl_xor(wpart, off, 64);
    const float ssum = wpart + wself;

    // combine quarters -> all lanes hold full sums for their sub
    a0 += __shfl_xor(a0, 16, 64); a0 += __shfl_xor(a0, 32, 64);
    a1 += __shfl_xor(a1, 16, 64); a1 += __shfl_xor(a1, 32, 64);
    a2 += __shfl_xor(a2, 16, 64); a2 += __shfl_xor(a2, 32, 64);
    a3 += __shfl_xor(a3, 16, 64); a3 += __shfl_xor(a3, 32, 64);

    // self term (post-combine: counted once)
    {
        uint2 sv = *(const uint2*)(hbb + (((unsigned int)n << 7) + suboff));
        a0 = fmaf(wself, bflo(sv.x), a0);
        a1 = fmaf(wself, bfhi(sv.x), a1);
        a2 = fmaf(wself, bflo(sv.y), a2);
        a3 = fmaf(wself, bfhi(sv.y), a3);
    }

    if (lane < NSUB) {                     // quarter 0, valid subs only
        const float inv = 1.f / (ssum + 1e-16f);
        float4 bv = *(const float4*)(bias + sub * 4);
        float4 o;
        o.x = a0 * inv + bv.x;
        o.y = a1 * inv + bv.y;
        o.z = a2 * inv + bv.z;
        o.w = a3 * inv + bv.w;
        if (RELU) {
            o.x = fmaxf(o.x, 0.f); o.y = fmaxf(o.y, 0.f);
            o.z = fmaxf(o.z, 0.f); o.w = fmaxf(o.w, 0.f);
        }
        *(float4*)(OUT + (size_t)n * FOUT + sub * 4) = o;
    }
}

// -------------------- pipelined agg layer 2, fused layer-3 GEMM (R17) -------

__global__ __launch_bounds__(256) void agg_pipe_h3_kernel(
    const int* __restrict__ rowptr, const int* __restrict__ csr,
    const float* __restrict__ asrc, const float* __restrict__ adst,
    const unsigned short* __restrict__ hb, const float* __restrict__ bias,
    const float* __restrict__ W3, float* __restrict__ h3, int N) {
    constexpr int FOUT = 60;
    constexpr int NSUB = FOUT / 4;         // 15
    __shared__ int   offlds[4][64];
    __shared__ float wlds[4][64];
    const int wv = threadIdx.x >> 6;
    int n = blockIdx.x * 4 + wv;
    if (n >= N) return;
    const int lane = threadIdx.x & 63;
    const int q    = lane >> 4;
    const int sub  = lane & 15;
    const int subc = (sub < NSUB) ? sub : NSUB - 1;
    const unsigned int suboff = (unsigned int)subc * 8;
    const int rs = rowptr[n], re = rowptr[n + 1];
    const float ad_n = adst[n];
    const float wself = __expf(leaky(asrc[n] + ad_n));
    const char* hbb = (const char*)hb;

    float a0 = 0.f, a1 = 0.f, a2 = 0.f, a3 = 0.f;
    float wpart = 0.f;

    for (int base = rs; base < re; base += 64) {
        const int cnt = min(64, re - base);
        int ce = base + lane;
        if (ce >= re) ce = re - 1;
        int sv = csr[ce];
        int sidx = (lane < cnt) ? sv : n;
        offlds[wv][lane] = sidx << 7;
        float as = asrc[sidx];
        if (cnt <= 32) { GATHER_STEP(8) } else { GATHER_STEP(16) }
    }

#pragma unroll
    for (int off = 32; off; off >>= 1) wpart += __shfl_xor(wpart, off, 64);
    const float ssum = wpart + wself;

    a0 += __shfl_xor(a0, 16, 64); a0 += __shfl_xor(a0, 32, 64);
    a1 += __shfl_xor(a1, 16, 64); a1 += __shfl_xor(a1, 32, 64);
    a2 += __shfl_xor(a2, 16, 64); a2 += __shfl_xor(a2, 32, 64);
    a3 += __shfl_xor(a3, 16, 64); a3 += __shfl_xor(a3, 32, 64);

    {
        uint2 sv = *(const uint2*)(hbb + (((unsigned int)n << 7) + suboff));
        a0 = fmaf(wself, bflo(sv.x), a0);
        a1 = fmaf(wself, bfhi(sv.x), a1);
        a2 = fmaf(wself, bflo(sv.y), a2);
        a3 = fmaf(wself, bfhi(sv.y), a3);
    }

    // act2 = relu(acc/ssum + bias); fold layer-3 GEMM: t = dot(act2, W3)
    float t = 0.f;
    {
        const float inv = 1.f / (ssum + 1e-16f);
        float4 bv = *(const float4*)(bias + subc * 4);
        float4 wv3 = *(const float4*)(W3 + subc * 4);
        float o0 = fmaxf(a0 * inv + bv.x, 0.f);
        float o1 = fmaxf(a1 * inv + bv.y, 0.f);
        float o2 = fmaxf(a2 * inv + bv.z, 0.f);
        float o3 = fmaxf(a3 * inv + bv.w, 0.f);
        if (sub < NSUB)
            t = o0 * wv3.x + o1 * wv3.y + o2 * wv3.z + o3 * wv3.w;
    }
#pragma unroll
    for (int off = 8; off; off >>= 1) t += __shfl_xor(t, off, 64);   // within quarter
    if (lane == 0) h3[n] = t;
}

// -------------------- layer-3 aggregation --------------------

__global__ __launch_bounds__(256) void agg1_kernel(
    const int* __restrict__ rowptr, const int* __restrict__ csr,
    const float* __restrict__ h3,
    const float* __restrict__ as3p, const float* __restrict__ ad3p,
    const float* __restrict__ bias, float* __restrict__ OUT, int N) {
    int n = blockIdx.x * 4 + (threadIdx.x >> 6);
    if (n >= N) return;
    int lane = threadIdx.x & 63;
    int rs = rowptr[n], re = rowptr[n + 1];
    const float a_s = as3p[0];
    float hn = h3[n];
    float adn = ad3p[0] * hn;
    float wself = __expf(leaky(a_s * hn + adn));

    float ssum = 0.f, accv = 0.f;
    for (int e = rs + lane; e < re; e += 64) {
        float hs = h3[csr[e]];
        float w = __expf(leaky(a_s * hs + adn));
        ssum += w;
        accv = fmaf(w, hs, accv);
    }
#pragma unroll
    for (int off = 32; off; off >>= 1) {
        ssum += __shfl_xor(ssum, off, 64);
        accv += __shfl_xor(accv, off, 64);
    }
    ssum += wself;
    accv = fmaf(wself, hn, accv);
    if (lane == 0) OUT[n] = accv / (ssum + 1e-16f) + bias[0];
}

// -------------------- host launcher --------------------

extern "C" void kernel_launch(void* const* d_in, const int* in_sizes, int n_in,
                              void* d_out, int out_size, void* d_ws, size_t ws_size,
                              hipStream_t stream) {
    const float* x      = (const float*)d_in[0];
    const int*   ei     = (const int*)d_in[1];   // int32 per harness convention
    // d_in[2] = edge_attr: ignored by reference (no edge_dim)
    const float* W1  = (const float*)d_in[3];
    const float* as1 = (const float*)d_in[4];
    const float* ad1 = (const float*)d_in[5];
    const float* b1  = (const float*)d_in[6];
    const float* W2  = (const float*)d_in[7];
    const float* as2 = (const float*)d_in[8];
    const float* ad2 = (const float*)d_in[9];
    const float* b2  = (const float*)d_in[10];
    const float* W3  = (const float*)d_in[11];
    const float* as3 = (const float*)d_in[12];
    const float* ad3 = (const float*)d_in[13];
    const float* b3  = (const float*)d_in[14];

    const int N = in_sizes[0] / 256;   // 50000
    const int E = in_sizes[1] / 2;     // 1600000
    const int K = (N + (1 << BSHIFT) - 1) >> BSHIFT;   // 391 buckets

    char* p = (char*)d_ws;
    auto alloc = [&](size_t bytes) -> void* {
        void* r = (void*)p;
        p += ((bytes + 255) / 256) * 256;
        return r;
    };
    int*   gcursor = (int*)alloc(512 * 4);
    int*   rowptr  = (int*)alloc(((size_t)N + 1) * 4);
    int*   csr     = (int*)alloc((size_t)E * 4);
    unsigned short* hb = (unsigned short*)alloc((size_t)N * 64 * 2);  // bf16 H, 128B rows
    float* actbuf  = (float*)alloc((size_t)N * 48 * 4);               // act1 only
    float* h3      = (float*)alloc((size_t)N * 4);
    float* asrc    = (float*)alloc((size_t)N * 4);
    float* adst    = (float*)alloc((size_t)N * 4);
    // staged bucket regions (8 MB) alias actbuf (9.6 MB, dead until first agg):
    unsigned int* staged = (unsigned int*)actbuf;

    // ---- CSR build + gemm1 (fused dispatch: disjoint outputs, overlap) ----
    hipMemsetAsync(gcursor, 0, 512 * 4, stream);
    int cblocks = (E + CTILE - 1) / CTILE;
    int gblocks = (N + 63) / 64;
    coarse_gemm1_kernel<256><<<cblocks + gblocks, 256, 0, stream>>>(
        ei, staged, gcursor, E, K, cblocks,
        x, W1, as1, ad1, hb, asrc, adst, N);
    fine_sort_kernel<<<K, 256, 0, stream>>>(staged, gcursor, rowptr, csr, N, E);

    int ablocks = (N + 3) / 4;

    // ---- layer 1 agg: 48 cols, relu -> actbuf ----
    agg_pipe_kernel<48, true><<<ablocks, 256, 0, stream>>>(
        rowptr, csr, asrc, adst, hb, b1, actbuf, N);

    // ---- layer 2: 48 -> 60, relu, fused layer-3 GEMM in agg epilogue ----
    gemm_sgpr_kernel<48, 60, 15><<<gblocks, 256, 0, stream>>>(
        actbuf, W2, as2, ad2, hb, asrc, adst, N);
    agg_pipe_h3_kernel<<<ablocks, 256, 0, stream>>>(
        rowptr, csr, asrc, adst, hb, b2, W3, h3, N);

    // ---- layer 3 aggregation: straight to d_out ----
    agg1_kernel<<<ablocks, 256, 0, stream>>>(rowptr, csr, h3, as3, ad3, b3, (float*)d_out, N);
}